// Round 7
// baseline (269.089 us; speedup 1.0000x reference)
//
#include <hip/hip_runtime.h>
#include <stdint.h>
#include <math.h>

typedef float f4 __attribute__((ext_vector_type(4)));
typedef float f32x4 __attribute__((ext_vector_type(4)));
typedef short bf16x8 __attribute__((ext_vector_type(8)));
typedef _Float16 f16x8 __attribute__((ext_vector_type(8)));
typedef unsigned short u16;
typedef unsigned short u16x4 __attribute__((ext_vector_type(4)));

#define NPIX 16384

// d_out offsets (floats). Return order: M1, M2, M1flat, M2flat, Ir_map, Vi_map, IrA, ViA
#define O_M1   0l
#define O_M2   16777216l
#define O_M1F  33554432l
#define O_M2F  50331648l
#define O_IR   67108864l
#define O_VI   71303168l
#define O_IRA  75497472l
#define O_VIA  75563008l
#define FLATD  33554432l   // offset from M to its flat duplicate (same for M1,M2)

// ws offsets (bytes)
#define WS_SUMP 0        // 1024 floats (8t * 4b * 32s)
#define WS_MMXE 4096     // 16 uints (per tensor min/max encoded)
#define WS_MMXA 4160     // 2 uints (activation map min/max)
#define WS_MEAN 4224     // 8 floats
#define WS_MNT  4256     // 8 floats
#define WS_INV  4288     // 8 floats
#define WS_W1M  8192     // 73728 u16, w1 as f16 relaid [icc][k9][oc][ic32]
#define WS_AM   262144   // 65536 floats (activation map, 256 KB)
#define WS_WB   524288   // 262144 u16 (softmax W bf16, 512 KB)

struct EPtrs { const float* p[8]; };

__device__ __forceinline__ u16 f2bf(float x){
  unsigned u = __float_as_uint(x);
  unsigned r = (u + 0x7fffu + ((u >> 16) & 1u)) >> 16;   // RNE
  return (u16)r;
}
__device__ __forceinline__ float bf2f(u16 v){
  return __uint_as_float(((unsigned)v) << 16);
}
__device__ __forceinline__ u16 f2h(float x){
  _Float16 h = (_Float16)x;
  u16 r; __builtin_memcpy(&r, &h, 2);
  return r;
}
// monotone float<->uint map for deterministic atomic min/max
__device__ __forceinline__ unsigned fenc(float x){
  unsigned u = __float_as_uint(x);
  return (u & 0x80000000u) ? ~u : (u | 0x80000000u);
}
__device__ __forceinline__ float fdec(unsigned u){
  unsigned v = (u & 0x80000000u) ? (u & 0x7fffffffu) : ~u;
  return __uint_as_float(v);
}

// ---------------- weight re-layout (+ atomic init in block 0) ----------------
__global__ void k_prep(const float* __restrict__ w1, u16* __restrict__ w1m,
                       unsigned* mmxe, unsigned* mmxa){
  if (blockIdx.x == 0 && threadIdx.x < 9){
    int t = threadIdx.x;
    if (t < 8){ mmxe[2*t] = 0xFFFFFFFFu; mmxe[2*t+1] = 0u; }
    else      { mmxa[0] = 0xFFFFFFFFu; mmxa[1] = 0u; }
  }
  int i = blockIdx.x*256 + threadIdx.x;
  if (i < 73728){
    int ic32 = i & 31;
    int oc   = (i >> 5) & 63;
    int k9   = (i >> 11) % 9;
    int icc  = i / 18432;
    float v = w1[(oc*128 + icc*32 + ic32)*9 + k9];
    w1m[i] = f2h(v);
  }
}

// ---------------- per-tensor stats + Gram partials (MFMA bf16) ----------------
// grid 1024 = 8 tensors * 4 batch * 32 slices(512 n each). block 256.
// gram partials stored TRANSPOSED: gramT[d][c] so rr (consecutive c) vectorizes.
__global__ __launch_bounds__(256) void k_stats_gram(EPtrs eps,
    float* __restrict__ gram, float* __restrict__ sump, unsigned* __restrict__ mmxe){
  int bid = blockIdx.x;
  int t = bid >> 7; int rb = bid & 127; int b = rb >> 5; int s = rb & 31;
  const float* E = eps.p[t];
  __shared__ u16 lds[64*136];           // [c][n(128)+pad8] bf16
  __shared__ float red[768];
  int tid = threadIdx.x;
  int lane = tid & 63, wave = tid >> 6;
  f32x4 acc[4];
  #pragma unroll
  for (int i=0;i<4;++i) acc[i] = (f32x4){0.f,0.f,0.f,0.f};
  float vmin = 3.4e38f, vmax = -3.4e38f, vsum = 0.f;
  int rowS = tid >> 5;            // 0..7
  int colS = (tid & 31) * 4;      // 0..124
  int rA = wave*16 + (lane & 15);
  int kb = (lane >> 4) * 8;
  long nbase = (long)s * 512;
  for (int ch = 0; ch < 4; ++ch){
    long n0 = nbase + ch*128;
    __syncthreads();
    #pragma unroll
    for (int p = 0; p < 8; ++p){
      int row = p*8 + rowS;
      f4 v = *(const f4*)&E[(long)(b*64 + row)*NPIX + n0 + colS];
      vsum += v[0]+v[1]+v[2]+v[3];
      vmin = fminf(vmin, fminf(fminf(v[0],v[1]), fminf(v[2],v[3])));
      vmax = fmaxf(vmax, fmaxf(fmaxf(v[0],v[1]), fmaxf(v[2],v[3])));
      u16x4 w; w[0]=f2bf(v[0]); w[1]=f2bf(v[1]); w[2]=f2bf(v[2]); w[3]=f2bf(v[3]);
      *(u16x4*)&lds[row*136 + colS] = w;
    }
    __syncthreads();
    #pragma unroll
    for (int ks = 0; ks < 4; ++ks){
      bf16x8 a = *(bf16x8*)&lds[rA*136 + ks*32 + kb];
      #pragma unroll
      for (int cb = 0; cb < 4; ++cb){
        bf16x8 bb = *(bf16x8*)&lds[(cb*16 + (lane&15))*136 + ks*32 + kb];
        acc[cb] = __builtin_amdgcn_mfma_f32_16x16x32_bf16(a, bb, acc[cb], 0, 0, 0);
      }
    }
  }
  // gram partial write (transposed, vectorized): gramT[d][c0..c0+3]
  long gbase = ((long)((t*4 + b)*32 + s)) * 4096;
  int c0 = 16*wave + 4*(lane>>4);
  #pragma unroll
  for (int cb = 0; cb < 4; ++cb){
    int d = cb*16 + (lane & 15);
    f4 v = {acc[cb][0], acc[cb][1], acc[cb][2], acc[cb][3]};
    *(f4*)&gram[gbase + d*64 + c0] = v;
  }
  // stats reduce
  red[tid] = vsum; red[256+tid] = vmin; red[512+tid] = vmax;
  __syncthreads();
  for (int off = 128; off > 0; off >>= 1){
    if (tid < off){
      red[tid] += red[tid+off];
      red[256+tid] = fminf(red[256+tid], red[256+tid+off]);
      red[512+tid] = fmaxf(red[512+tid], red[512+tid+off]);
    }
    __syncthreads();
  }
  if (tid == 0){
    sump[t*128 + b*32 + s] = red[0];
    atomicMin(&mmxe[2*t], fenc(red[256]));
    atomicMax(&mmxe[2*t+1], fenc(red[512]));
  }
}

// ---------------- gramT 32-slice reduce + softmax over axis=1 + scalar finalize ----------------
// grid 32 = (t,b). block 1024. S relaid as [d][c] (stride 68). W[c][d] bf16 -> Wb (ws).
__global__ __launch_bounds__(1024) void k_softmax(const float* __restrict__ gram,
                          u16* __restrict__ Wb,
                          const float* __restrict__ sump, const unsigned* __restrict__ mmxe,
                          float* __restrict__ meanA, float* __restrict__ mntA, float* __restrict__ invA){
  int bid = blockIdx.x; int t = bid >> 2; int b = bid & 3;
  __shared__ float S[64*68];           // S[d][c]
  int tid = threadIdx.x;
  if (b == 0 && tid == 0){
    float s = 0.f;
    for (int j = 0; j < 128; ++j) s += sump[t*128 + j];
    float mean = s / 4194304.0f;
    float mn = fdec(mmxe[2*t]), mx = fdec(mmxe[2*t+1]);
    float mnt = fmaxf(mn - mean, 1e-10f);
    float mxt = fmaxf(mx - mean, 1e-10f);
    meanA[t] = mean; mntA[t] = mnt;
    invA[t] = 1.0f / (mxt - mnt + 1e-10f);
  }
  // reduce 32 partial gramTs (flat, same s-order -> bit-identical sums)
  long gb = (long)(t*4 + b)*32*4096;
  {
    int i = tid;                        // 1024 threads * 4 elems = 4096
    f4 a = (f4){0.f,0.f,0.f,0.f};
    #pragma unroll
    for (int s = 0; s < 32; ++s) a += *(const f4*)&gram[gb + s*4096 + i*4];
    int d = i >> 4, c0 = (i & 15)*4;    // flat = d*64 + c
    *(f4*)&S[d*68 + c0] = a;
  }
  __syncthreads();
  if (tid < 64){
    int d = tid;
    float mx = -3.4e38f;
    for (int c = 0; c < 64; ++c) mx = fmaxf(mx, S[d*68+c]);
    float sum = 0.f;
    for (int c = 0; c < 64; ++c){ float e = expf(S[d*68+c]-mx); S[d*68+c] = e; sum += e; }
    float inv = 1.0f/sum;
    long wb = (long)(t*4 + b)*4096;
    for (int c = 0; c < 64; ++c) Wb[wb + c*64 + d] = f2bf(S[d*68+c]*inv);
  }
}

// ---------------- conv1 3x3 implicit-GEMM MFMA f16 + bias + leaky ----------------
// grid 512 = (b,h) XCD-swizzled. block 512 = 8 waves: wave = (mg 2) x (ng 4).
__global__ __launch_bounds__(512) void k_conv1(const float* __restrict__ fc,
    const u16* __restrict__ w1m, const float* __restrict__ b1, float* __restrict__ cat){
  int bid = blockIdx.x;
  int vb = (bid & 7)*64 + (bid >> 3);      // XCD-chunked: contiguous h-bands per XCD
  int b = vb >> 7, h = vb & 127;
  __shared__ u16 xin[32*3*140];            // [ic32][r3][s140] f16 bits; s = w_in + 4
  int tid = threadIdx.x;
  int lane = tid & 63, wv = tid >> 6;
  int mg = wv >> 2, ng = wv & 3;
  int l15 = lane & 15, lq = lane >> 4;
  if (tid < 192){
    int ic = tid / 6, rem = tid % 6;
    int r = rem >> 1, sx = (rem & 1) ? 132 : 3;
    xin[(ic*3 + r)*140 + sx] = 0;
  }
  f32x4 acc[2][2];
  #pragma unroll
  for (int i=0;i<2;++i)
    #pragma unroll
    for (int j=0;j<2;++j) acc[i][j] = (f32x4){0.f,0.f,0.f,0.f};
  for (int icc = 0; icc < 4; ++icc){
    __syncthreads();
    #pragma unroll
    for (int it = 0; it < 6; ++it){
      int idx = tid + it*512;              // < 3072
      int ic = idx / 96, rem = idx % 96;
      int r = rem >> 5, q = rem & 31;
      int hr = h + r - 1;
      f4 v = (f4){0.f,0.f,0.f,0.f};
      if ((unsigned)hr < 128u)
        v = *(const f4*)&fc[(long)((b*128 + icc*32 + ic)*128 + hr)*128 + 4*q];
      u16x4 w; w[0]=f2h(v[0]); w[1]=f2h(v[1]); w[2]=f2h(v[2]); w[3]=f2h(v[3]);
      *(u16x4*)&xin[(ic*3 + r)*140 + 4 + 4*q] = w;
    }
    __syncthreads();
    #pragma unroll
    for (int kh = 0; kh < 3; ++kh){
      #pragma unroll
      for (int kw = 0; kw < 3; ++kw){
        int k9 = kh*3 + kw;
        f16x8 A[2];
        #pragma unroll
        for (int mi = 0; mi < 2; ++mi){
          int m = mg*2 + mi;
          A[mi] = *(const f16x8*)&w1m[(((icc*9 + k9)*64) + m*16 + l15)*32 + lq*8];
        }
        #pragma unroll
        for (int ji = 0; ji < 2; ++ji){
          int s = ng*32 + ji*16 + l15 + kw + 3;
          int kb = lq*8;
          f16x8 bv;
          #pragma unroll
          for (int e = 0; e < 8; ++e){
            u16 raw = xin[((kb + e)*3 + kh)*140 + s];
            _Float16 hh; __builtin_memcpy(&hh, &raw, 2);
            bv[e] = hh;
          }
          acc[0][ji] = __builtin_amdgcn_mfma_f32_16x16x32_f16(A[0], bv, acc[0][ji], 0, 0, 0);
          acc[1][ji] = __builtin_amdgcn_mfma_f32_16x16x32_f16(A[1], bv, acc[1][ji], 0, 0, 0);
        }
      }
    }
  }
  #pragma unroll
  for (int mi = 0; mi < 2; ++mi){
    #pragma unroll
    for (int rr = 0; rr < 4; ++rr){
      int oc = (mg*2 + mi)*16 + lq*4 + rr;
      float bb = b1[oc];
      #pragma unroll
      for (int ji = 0; ji < 2; ++ji){
        int w = ng*32 + ji*16 + l15;
        float v = acc[mi][ji][rr] + bb;
        v = v > 0.f ? v : 0.01f*v;
        cat[(long)((b*64 + oc)*128 + h)*128 + w] = v;
      }
    }
  }
}

// ---------------- conv2 3x3 (64ch -> 1) + bias, plus global min/max of result ----------------
// grid 512 = (b,h). block 256. am -> ws.
__global__ __launch_bounds__(256) void k_conv2(const float* __restrict__ cat,
    const float* __restrict__ w2, const float* __restrict__ b2p,
    float* __restrict__ am, unsigned* __restrict__ mmxa){
  int bid = blockIdx.x; int b = bid >> 7; int h = bid & 127;
  __shared__ u16 l2[64*3*136];
  __shared__ float w2l[576];
  __shared__ float red2[256];
  int tid = threadIdx.x;
  for (int i = tid; i < 576; i += 256) w2l[i] = w2[i];
  if (tid < 192){
    int ic = tid / 3, r = tid % 3;
    l2[ic*408 + r*136 + 3]   = 0;   // w_in = -1
    l2[ic*408 + r*136 + 132] = 0;   // w_in = 128
  }
  #pragma unroll
  for (int rep = 0; rep < 3; ++rep){
    int idx = rep*256 + tid;             // < 768 = 64ic * 3r * 4q
    int ic = idx / 12; int rem = idx - ic*12; int r = rem >> 2; int q = rem & 3;
    int hr = h + r - 1;
    #pragma unroll
    for (int k = 0; k < 8; ++k){
      int w = q*32 + 4*k;
      f4 v = (f4){0.f,0.f,0.f,0.f};
      if ((unsigned)hr < 128u)
        v = *(const f4*)&cat[(long)((b*64 + ic)*128 + hr)*128 + w];
      u16x4 u; u[0]=f2bf(v[0]); u[1]=f2bf(v[1]); u[2]=f2bf(v[2]); u[3]=f2bf(v[3]);
      *(u16x4*)&l2[ic*408 + r*136 + 4 + w] = u;
    }
  }
  __syncthreads();
  int w = tid & 127, icg = tid >> 7;
  float a = 0.f;
  for (int ic = icg*32; ic < icg*32+32; ++ic){
    #pragma unroll
    for (int r = 0; r < 3; ++r)
      #pragma unroll
      for (int kw = 0; kw < 3; ++kw)
        a = fmaf(bf2f(l2[ic*408 + r*136 + (w + kw + 3)]), w2l[ic*9 + r*3 + kw], a);
  }
  red2[tid] = a;
  __syncthreads();
  float av = 0.f;
  if (icg == 0){
    av = red2[w] + red2[128 + w] + b2p[0];
    am[(long)(b*128 + h)*128 + w] = av;
  }
  __syncthreads();
  red2[tid] = (icg == 0) ? av : -3.4e38f;
  __syncthreads();
  for (int off = 128; off > 0; off >>= 1){
    if (tid < off) red2[tid] = fmaxf(red2[tid], red2[tid+off]);
    __syncthreads();
  }
  if (tid == 0) atomicMax(&mmxa[1], fenc(red2[0]));
  __syncthreads();
  red2[tid] = (icg == 0) ? av : 3.4e38f;
  __syncthreads();
  for (int off = 128; off > 0; off >>= 1){
    if (tid < off) red2[tid] = fminf(red2[tid], red2[tid+off]);
    __syncthreads();
  }
  if (tid == 0) atomicMin(&mmxa[0], fenc(red2[0]));
}

// ---------------- Ir/Vi maps (cat in O_IR, in-place) + folded activation outputs ----------------
// grid 4096, block 256. tid<4 additionally handle one f4 of the IrA/ViA outputs.
__global__ void k_maps(const float* __restrict__ am,
                       const unsigned* __restrict__ mmxa, float* __restrict__ out){
  int bid = blockIdx.x;
  int tid = threadIdx.x;
  float mn = fdec(mmxa[0]);
  float inv = 1.0f / (fdec(mmxa[1]) - mn + 1e-10f);
  long e = ((long)bid*256 + tid) * 4;
  f4 c = *(const f4*)&out[O_IR + e];
  f4 a = *(const f4*)&am[(e >> 20)*16384 + (e & 16383)];
  f4 nam = (a - mn) * inv;
  f4 ir = nam * c;
  f4 vi = (1.0f - nam) * c;
  *(f4*)&out[O_IR + e] = ir;
  *(f4*)&out[O_VI + e] = vi;
  if (tid < 4){
    long e2 = ((long)bid*4 + tid) * 4;   // 16384 quads = 65536 floats
    f4 a2 = *(const f4*)&am[e2];
    f4 nam2 = (a2 - mn) * inv;
    *(f4*)&out[O_IRA + e2] = nam2;
    *(f4*)&out[O_VIA + e2] = 1.0f - nam2;
  }
}

// ---------------- fuse: stage E tile in LDS (f32, swizzled), MFMA fw, LDS-restaged epilogue ----------------
// grid 4096 = 8t * 4b * 128 nt(128 n). block 256 = 4 waves; wave w -> 32 n.
// in-tile: elem (c,n) at n*64 + (((c>>2)^(n&15))<<2) + (c&3).
// out-tile (reuses same LDS after barrier): elem (c,n) at c*128 + ((n + 4*c) & 127).
__global__ __launch_bounds__(256, 4) void k_fuse(EPtrs eps, const u16* __restrict__ Wb,
    const float* __restrict__ meanA, const float* __restrict__ mntA, const float* __restrict__ invA,
    float* __restrict__ out){
  int bid = blockIdx.x;
  int t = bid >> 9; int rem = bid & 511; int b = rem >> 7; int nt = rem & 127;
  const float* E = eps.p[t];
  const u16* Wp = Wb + (long)(t*4 + b)*4096;
  __shared__ float tileF[8192];       // 32 KB
  int tid = threadIdx.x; int lane = tid & 63; int w = tid >> 6;
  int jc = lane & 15, lq = lane >> 4;
  long n0 = (long)nt * 128;
  long eb = (long)(b*64) * NPIX;
  bf16x8 A[2][4];
  #pragma unroll
  for (int ks = 0; ks < 2; ++ks)
    #pragma unroll
    for (int mi = 0; mi < 4; ++mi)
      A[ks][mi] = *(const bf16x8*)&Wp[(mi*16 + jc)*64 + ks*32 + lq*8];
  #pragma unroll
  for (int it = 0; it < 8; ++it){
    int a = it*4 + w;                  // 0..31
    int c0 = (a >> 1) << 2;
    int n = (a & 1)*64 + lane;
    long src = eb + (long)c0*NPIX + n0 + n;
    float f0 = E[src];
    float f1 = E[src + NPIX];
    float f2 = E[src + 2*NPIX];
    float f3 = E[src + 3*NPIX];
    f32x4 v = {f0, f1, f2, f3};
    *(f32x4*)&tileF[n*64 + (((c0 >> 2) ^ (n & 15)) << 2)] = v;
  }
  __syncthreads();
  f32x4 acc[4][2];
  #pragma unroll
  for (int i=0;i<4;++i)
    #pragma unroll
    for (int j=0;j<2;++j) acc[i][j] = (f32x4){0.f,0.f,0.f,0.f};
  int nw = w*32;
  #pragma unroll
  for (int ks = 0; ks < 2; ++ks){
    #pragma unroll
    for (int j = 0; j < 2; ++j){
      int n_t = nw + j*16 + jc;        // n_t & 15 == jc
      int p = ks*8 + lq*2;
      const float* base = &tileF[n_t*64];
      f32x4 q0 = *(const f32x4*)&base[(p ^ jc) << 2];
      f32x4 q1 = *(const f32x4*)&base[((p+1) ^ jc) << 2];
      bf16x8 bv;
      bv[0]=(short)f2bf(q0[0]); bv[1]=(short)f2bf(q0[1]);
      bv[2]=(short)f2bf(q0[2]); bv[3]=(short)f2bf(q0[3]);
      bv[4]=(short)f2bf(q1[0]); bv[5]=(short)f2bf(q1[1]);
      bv[6]=(short)f2bf(q1[2]); bv[7]=(short)f2bf(q1[3]);
      #pragma unroll
      for (int mi = 0; mi < 4; ++mi)
        acc[mi][j] = __builtin_amdgcn_mfma_f32_16x16x32_bf16(A[ks][mi], bv, acc[mi][j], 0, 0, 0);
    }
  }
  float mean = meanA[t], mnt = mntA[t], inv = invA[t];
  // fold epilogue values into acc (reads E f32 from in-tile)
  #pragma unroll
  for (int mi = 0; mi < 4; ++mi){
    #pragma unroll
    for (int j = 0; j < 2; ++j){
      int n_t = nw + j*16 + jc;
      f32x4 fv = *(const f32x4*)&tileF[n_t*64 + (((mi*4 + lq) ^ jc) << 2)];
      #pragma unroll
      for (int rr = 0; rr < 4; ++rr){
        float f = fv[rr];
        float tv = fmaxf(f - mean, 1e-10f);
        acc[mi][j][rr] = (tv - mnt)*inv + acc[mi][j][rr] + f;
      }
    }
  }
  __syncthreads();                    // in-tile fully consumed
  // restage result into out-tile layout
  #pragma unroll
  for (int mi = 0; mi < 4; ++mi){
    #pragma unroll
    for (int j = 0; j < 2; ++j){
      int n_t = nw + j*16 + jc;
      #pragma unroll
      for (int rr = 0; rr < 4; ++rr){
        int c = mi*16 + lq*4 + rr;
        tileF[c*128 + ((n_t + 4*c) & 127)] = acc[mi][j][rr];
      }
    }
  }
  __syncthreads();
  // vectorized stores: thread -> c = tid>>2, n = (tid&3)*32 + 4k
  long Mbase = (t & 1) ? O_M2 : O_M1;
  long gr = t >> 1;
  int c = tid >> 2;
  int nb = (tid & 3) * 32;
  long dst = Mbase + ((long)(b*256 + gr*64 + c))*NPIX + n0 + nb;
  const float* row = &tileF[c*128];
  int sw = 4*c;
  #pragma unroll
  for (int k = 0; k < 8; ++k){
    int n = nb + 4*k;
    f4 v = *(const f4*)&row[(n + sw) & 127];
    *(f4*)&out[dst + 4*k] = v;
    *(f4*)&out[dst + 4*k + FLATD] = v;
  }
}

extern "C" void kernel_launch(void* const* d_in, const int* in_sizes, int n_in,
                              void* d_out, int out_size, void* d_ws, size_t ws_size,
                              hipStream_t stream){
  (void)in_sizes; (void)n_in; (void)out_size; (void)ws_size;
  EPtrs ep;
  for (int i = 0; i < 8; ++i) ep.p[i] = (const float*)d_in[i];
  const float* fc = (const float*)d_in[8];
  const float* w1 = (const float*)d_in[9];
  const float* b1 = (const float*)d_in[10];
  const float* w2 = (const float*)d_in[11];
  const float* b2 = (const float*)d_in[12];
  float* out = (float*)d_out;
  char* ws = (char*)d_ws;
  float* sump   = (float*)(ws + WS_SUMP);
  unsigned* mmxe = (unsigned*)(ws + WS_MMXE);
  unsigned* mmxa = (unsigned*)(ws + WS_MMXA);
  float* meanA  = (float*)(ws + WS_MEAN);
  float* mntA   = (float*)(ws + WS_MNT);
  float* invA   = (float*)(ws + WS_INV);
  u16*   w1m    = (u16*)(ws + WS_W1M);
  float* am     = (float*)(ws + WS_AM);
  u16*   Wb     = (u16*)(ws + WS_WB);
  // d_out-aliased scratch:
  float* gram = out + O_M1F;            // written stats, read softmax, overwritten fuse
  float* cat  = out + O_IR;             // written conv1, read conv2 + maps(in-place)

  k_prep      <<<288, 256, 0, stream>>>(w1, w1m, mmxe, mmxa);
  k_conv1     <<<512, 512, 0, stream>>>(fc, w1m, b1, cat);
  k_conv2     <<<512, 256, 0, stream>>>(cat, w2, b2, am, mmxa);
  k_maps      <<<4096,256, 0, stream>>>(am, mmxa, out);
  k_stats_gram<<<1024,256, 0, stream>>>(ep, gram, sump, mmxe);
  k_softmax   <<<32, 1024, 0, stream>>>(gram, Wb, sump, mmxe, meanA, mntA, invA);
  k_fuse      <<<4096,256, 0, stream>>>(ep, Wb, meanA, mntA, invA, out);
}

// Round 8
// 205.888 us; speedup vs baseline: 1.3070x; 1.3070x over previous
//
#include <hip/hip_runtime.h>
#include <stdint.h>
#include <math.h>

typedef float f4 __attribute__((ext_vector_type(4)));
typedef float f32x4 __attribute__((ext_vector_type(4)));
typedef short bf16x8 __attribute__((ext_vector_type(8)));
typedef _Float16 f16x8 __attribute__((ext_vector_type(8)));
typedef unsigned short u16;
typedef unsigned short u16x4 __attribute__((ext_vector_type(4)));

#define NPIX 16384

// d_out offsets (floats). Return order: M1, M2, M1flat, M2flat, Ir_map, Vi_map, IrA, ViA
#define O_M1   0l
#define O_M2   16777216l
#define O_M1F  33554432l
#define O_M2F  50331648l
#define O_IR   67108864l
#define O_VI   71303168l
#define O_IRA  75497472l
#define O_VIA  75563008l
#define FLATD  33554432l   // offset from M to its flat duplicate (same for M1,M2)

// ws offsets (bytes)
#define WS_SUMP 0        // 1024 floats (8t * 4b * 32s)
#define WS_MMXE 4096     // 16 uints (per tensor min/max encoded)
#define WS_MMXA 4160     // 2 uints (activation map min/max)
#define WS_MEAN 4224     // 8 floats
#define WS_MNT  4256     // 8 floats
#define WS_INV  4288     // 8 floats
#define WS_W1M  8192     // 73728 u16, w1 as f16 relaid [icc][k9][oc][ic32]
#define WS_AM   262144   // 65536 floats (activation map, 256 KB)
#define WS_WB   524288   // 262144 u16 (softmax W bf16, 512 KB)

struct EPtrs { const float* p[8]; };

__device__ __forceinline__ u16 f2bf(float x){
  unsigned u = __float_as_uint(x);
  unsigned r = (u + 0x7fffu + ((u >> 16) & 1u)) >> 16;   // RNE
  return (u16)r;
}
__device__ __forceinline__ float bf2f(u16 v){
  return __uint_as_float(((unsigned)v) << 16);
}
__device__ __forceinline__ u16 f2h(float x){
  _Float16 h = (_Float16)x;
  u16 r; __builtin_memcpy(&r, &h, 2);
  return r;
}
// monotone float<->uint map for deterministic atomic min/max
__device__ __forceinline__ unsigned fenc(float x){
  unsigned u = __float_as_uint(x);
  return (u & 0x80000000u) ? ~u : (u | 0x80000000u);
}
__device__ __forceinline__ float fdec(unsigned u){
  unsigned v = (u & 0x80000000u) ? (u & 0x7fffffffu) : ~u;
  return __uint_as_float(v);
}

// ---------------- weight re-layout (+ atomic init in block 0) ----------------
__global__ void k_prep(const float* __restrict__ w1, u16* __restrict__ w1m,
                       unsigned* mmxe, unsigned* mmxa){
  if (blockIdx.x == 0 && threadIdx.x < 9){
    int t = threadIdx.x;
    if (t < 8){ mmxe[2*t] = 0xFFFFFFFFu; mmxe[2*t+1] = 0u; }
    else      { mmxa[0] = 0xFFFFFFFFu; mmxa[1] = 0u; }
  }
  int i = blockIdx.x*256 + threadIdx.x;
  if (i < 73728){
    int ic32 = i & 31;
    int oc   = (i >> 5) & 63;
    int k9   = (i >> 11) % 9;
    int icc  = i / 18432;
    float v = w1[(oc*128 + icc*32 + ic32)*9 + k9];
    w1m[i] = f2h(v);
  }
}

// ---------------- per-tensor stats + Gram partials (MFMA bf16) ----------------
// grid 1024 = 8 tensors * 4 batch * 32 slices(512 n each). block 256.
__global__ __launch_bounds__(256) void k_stats_gram(EPtrs eps,
    float* __restrict__ gram, float* __restrict__ sump, unsigned* __restrict__ mmxe){
  int bid = blockIdx.x;
  int t = bid >> 7; int rb = bid & 127; int b = rb >> 5; int s = rb & 31;
  const float* E = eps.p[t];
  __shared__ u16 lds[64*136];           // [c][n(128)+pad8] bf16
  __shared__ float red[768];
  int tid = threadIdx.x;
  int lane = tid & 63, wave = tid >> 6;
  f32x4 acc[4];
  #pragma unroll
  for (int i=0;i<4;++i) acc[i] = (f32x4){0.f,0.f,0.f,0.f};
  float vmin = 3.4e38f, vmax = -3.4e38f, vsum = 0.f;
  int rowS = tid >> 5;            // 0..7
  int colS = (tid & 31) * 4;      // 0..124
  int rA = wave*16 + (lane & 15);
  int kb = (lane >> 4) * 8;
  long nbase = (long)s * 512;
  for (int ch = 0; ch < 4; ++ch){
    long n0 = nbase + ch*128;
    __syncthreads();
    #pragma unroll
    for (int p = 0; p < 8; ++p){
      int row = p*8 + rowS;
      f4 v = *(const f4*)&E[(long)(b*64 + row)*NPIX + n0 + colS];
      vsum += v[0]+v[1]+v[2]+v[3];
      vmin = fminf(vmin, fminf(fminf(v[0],v[1]), fminf(v[2],v[3])));
      vmax = fmaxf(vmax, fmaxf(fmaxf(v[0],v[1]), fmaxf(v[2],v[3])));
      u16x4 w; w[0]=f2bf(v[0]); w[1]=f2bf(v[1]); w[2]=f2bf(v[2]); w[3]=f2bf(v[3]);
      *(u16x4*)&lds[row*136 + colS] = w;
    }
    __syncthreads();
    #pragma unroll
    for (int ks = 0; ks < 4; ++ks){
      bf16x8 a = *(bf16x8*)&lds[rA*136 + ks*32 + kb];
      #pragma unroll
      for (int cb = 0; cb < 4; ++cb){
        bf16x8 bb = *(bf16x8*)&lds[(cb*16 + (lane&15))*136 + ks*32 + kb];
        acc[cb] = __builtin_amdgcn_mfma_f32_16x16x32_bf16(a, bb, acc[cb], 0, 0, 0);
      }
    }
  }
  // gram partial write: S[c][d], c = 16*wave + 4*(lane>>4)+rr, d = 16*cb + (lane&15)
  long gbase = ((long)((t*4 + b)*32 + s)) * 4096;
  #pragma unroll
  for (int cb = 0; cb < 4; ++cb){
    int d = cb*16 + (lane & 15);
    #pragma unroll
    for (int rr = 0; rr < 4; ++rr){
      int c = 16*wave + 4*(lane>>4) + rr;
      gram[gbase + c*64 + d] = acc[cb][rr];
    }
  }
  // stats reduce
  red[tid] = vsum; red[256+tid] = vmin; red[512+tid] = vmax;
  __syncthreads();
  for (int off = 128; off > 0; off >>= 1){
    if (tid < off){
      red[tid] += red[tid+off];
      red[256+tid] = fminf(red[256+tid], red[256+tid+off]);
      red[512+tid] = fmaxf(red[512+tid], red[512+tid+off]);
    }
    __syncthreads();
  }
  if (tid == 0){
    sump[t*128 + b*32 + s] = red[0];
    atomicMin(&mmxe[2*t], fenc(red[256]));
    atomicMax(&mmxe[2*t+1], fenc(red[512]));
  }
}

// ---------------- gram 32-slice reduce + softmax over axis=1 + scalar finalize ----------------
// grid 32 = (t,b). block 1024. W[c][d] bf16 written to Wb (ws).
__global__ __launch_bounds__(1024) void k_softmax(const float* __restrict__ gram,
                          u16* __restrict__ Wb,
                          const float* __restrict__ sump, const unsigned* __restrict__ mmxe,
                          float* __restrict__ meanA, float* __restrict__ mntA, float* __restrict__ invA){
  int bid = blockIdx.x; int t = bid >> 2; int b = bid & 3;
  __shared__ float S[64*68];
  int tid = threadIdx.x;
  if (b == 0 && tid == 0){
    float s = 0.f;
    for (int j = 0; j < 128; ++j) s += sump[t*128 + j];
    float mean = s / 4194304.0f;
    float mn = fdec(mmxe[2*t]), mx = fdec(mmxe[2*t+1]);
    float mnt = fmaxf(mn - mean, 1e-10f);
    float mxt = fmaxf(mx - mean, 1e-10f);
    meanA[t] = mean; mntA[t] = mnt;
    invA[t] = 1.0f / (mxt - mnt + 1e-10f);
  }
  // reduce 32 partial grams (L2/L3-hot) -> S; same s-order as before (bit-identical)
  long gb = (long)(t*4 + b)*32*4096;
  {
    int i = tid;                        // 1024 threads * 4 elems = 4096
    f4 a = (f4){0.f,0.f,0.f,0.f};
    #pragma unroll
    for (int s = 0; s < 32; ++s) a += *(const f4*)&gram[gb + s*4096 + i*4];
    int c = i >> 4, d0 = (i & 15)*4;
    *(f4*)&S[c*68 + d0] = a;
  }
  __syncthreads();
  if (tid < 64){
    int d = tid;
    float mx = -3.4e38f;
    for (int c = 0; c < 64; ++c) mx = fmaxf(mx, S[c*68+d]);
    float sum = 0.f;
    for (int c = 0; c < 64; ++c){ float e = expf(S[c*68+d]-mx); S[c*68+d] = e; sum += e; }
    float inv = 1.0f/sum;
    long wb = (long)(t*4 + b)*4096;
    for (int c = 0; c < 64; ++c) Wb[wb + c*64 + d] = f2bf(S[c*68+d]*inv);
  }
}

// ---------------- conv1 3x3 implicit-GEMM MFMA f16 + bias + leaky ----------------
// grid 512 = (b,h) XCD-swizzled. block 512 = 8 waves: wave = (mg 2) x (ng 4).
__global__ __launch_bounds__(512) void k_conv1(const float* __restrict__ fc,
    const u16* __restrict__ w1m, const float* __restrict__ b1, float* __restrict__ cat){
  int bid = blockIdx.x;
  int vb = (bid & 7)*64 + (bid >> 3);      // XCD-chunked: contiguous h-bands per XCD
  int b = vb >> 7, h = vb & 127;
  __shared__ u16 xin[32*3*140];            // [ic32][r3][s140] f16 bits; s = w_in + 4
  int tid = threadIdx.x;
  int lane = tid & 63, wv = tid >> 6;
  int mg = wv >> 2, ng = wv & 3;
  int l15 = lane & 15, lq = lane >> 4;
  if (tid < 192){
    int ic = tid / 6, rem = tid % 6;
    int r = rem >> 1, sx = (rem & 1) ? 132 : 3;
    xin[(ic*3 + r)*140 + sx] = 0;
  }
  f32x4 acc[2][2];
  #pragma unroll
  for (int i=0;i<2;++i)
    #pragma unroll
    for (int j=0;j<2;++j) acc[i][j] = (f32x4){0.f,0.f,0.f,0.f};
  for (int icc = 0; icc < 4; ++icc){
    __syncthreads();
    #pragma unroll
    for (int it = 0; it < 6; ++it){
      int idx = tid + it*512;              // < 3072
      int ic = idx / 96, rem = idx % 96;
      int r = rem >> 5, q = rem & 31;
      int hr = h + r - 1;
      f4 v = (f4){0.f,0.f,0.f,0.f};
      if ((unsigned)hr < 128u)
        v = *(const f4*)&fc[(long)((b*128 + icc*32 + ic)*128 + hr)*128 + 4*q];
      u16x4 w; w[0]=f2h(v[0]); w[1]=f2h(v[1]); w[2]=f2h(v[2]); w[3]=f2h(v[3]);
      *(u16x4*)&xin[(ic*3 + r)*140 + 4 + 4*q] = w;
    }
    __syncthreads();
    #pragma unroll
    for (int kh = 0; kh < 3; ++kh){
      #pragma unroll
      for (int kw = 0; kw < 3; ++kw){
        int k9 = kh*3 + kw;
        f16x8 A[2];
        #pragma unroll
        for (int mi = 0; mi < 2; ++mi){
          int m = mg*2 + mi;
          A[mi] = *(const f16x8*)&w1m[(((icc*9 + k9)*64) + m*16 + l15)*32 + lq*8];
        }
        #pragma unroll
        for (int ji = 0; ji < 2; ++ji){
          int s = ng*32 + ji*16 + l15 + kw + 3;
          int kb = lq*8;
          f16x8 bv;
          #pragma unroll
          for (int e = 0; e < 8; ++e){
            u16 raw = xin[((kb + e)*3 + kh)*140 + s];
            _Float16 hh; __builtin_memcpy(&hh, &raw, 2);
            bv[e] = hh;
          }
          acc[0][ji] = __builtin_amdgcn_mfma_f32_16x16x32_f16(A[0], bv, acc[0][ji], 0, 0, 0);
          acc[1][ji] = __builtin_amdgcn_mfma_f32_16x16x32_f16(A[1], bv, acc[1][ji], 0, 0, 0);
        }
      }
    }
  }
  #pragma unroll
  for (int mi = 0; mi < 2; ++mi){
    #pragma unroll
    for (int rr = 0; rr < 4; ++rr){
      int oc = (mg*2 + mi)*16 + lq*4 + rr;
      float bb = b1[oc];
      #pragma unroll
      for (int ji = 0; ji < 2; ++ji){
        int w = ng*32 + ji*16 + l15;
        float v = acc[mi][ji][rr] + bb;
        v = v > 0.f ? v : 0.01f*v;
        cat[(long)((b*64 + oc)*128 + h)*128 + w] = v;
      }
    }
  }
}

// ---------------- conv2 3x3 (64ch -> 1) + bias, plus global min/max of result ----------------
// grid 512 = (b,h). block 256. am -> ws.
__global__ __launch_bounds__(256) void k_conv2(const float* __restrict__ cat,
    const float* __restrict__ w2, const float* __restrict__ b2p,
    float* __restrict__ am, unsigned* __restrict__ mmxa){
  int bid = blockIdx.x; int b = bid >> 7; int h = bid & 127;
  __shared__ u16 l2[64*3*136];
  __shared__ float w2l[576];
  __shared__ float red2[256];
  int tid = threadIdx.x;
  for (int i = tid; i < 576; i += 256) w2l[i] = w2[i];
  if (tid < 192){
    int ic = tid / 3, r = tid % 3;
    l2[ic*408 + r*136 + 3]   = 0;   // w_in = -1
    l2[ic*408 + r*136 + 132] = 0;   // w_in = 128
  }
  #pragma unroll
  for (int rep = 0; rep < 3; ++rep){
    int idx = rep*256 + tid;             // < 768 = 64ic * 3r * 4q
    int ic = idx / 12; int rem = idx - ic*12; int r = rem >> 2; int q = rem & 3;
    int hr = h + r - 1;
    #pragma unroll
    for (int k = 0; k < 8; ++k){
      int w = q*32 + 4*k;
      f4 v = (f4){0.f,0.f,0.f,0.f};
      if ((unsigned)hr < 128u)
        v = *(const f4*)&cat[(long)((b*64 + ic)*128 + hr)*128 + w];
      u16x4 u; u[0]=f2bf(v[0]); u[1]=f2bf(v[1]); u[2]=f2bf(v[2]); u[3]=f2bf(v[3]);
      *(u16x4*)&l2[ic*408 + r*136 + 4 + w] = u;
    }
  }
  __syncthreads();
  int w = tid & 127, icg = tid >> 7;
  float a = 0.f;
  for (int ic = icg*32; ic < icg*32+32; ++ic){
    #pragma unroll
    for (int r = 0; r < 3; ++r)
      #pragma unroll
      for (int kw = 0; kw < 3; ++kw)
        a = fmaf(bf2f(l2[ic*408 + r*136 + (w + kw + 3)]), w2l[ic*9 + r*3 + kw], a);
  }
  red2[tid] = a;
  __syncthreads();
  float av = 0.f;
  if (icg == 0){
    av = red2[w] + red2[128 + w] + b2p[0];
    am[(long)(b*128 + h)*128 + w] = av;
  }
  __syncthreads();
  red2[tid] = (icg == 0) ? av : -3.4e38f;
  __syncthreads();
  for (int off = 128; off > 0; off >>= 1){
    if (tid < off) red2[tid] = fmaxf(red2[tid], red2[tid+off]);
    __syncthreads();
  }
  if (tid == 0) atomicMax(&mmxa[1], fenc(red2[0]));
  __syncthreads();
  red2[tid] = (icg == 0) ? av : 3.4e38f;
  __syncthreads();
  for (int off = 128; off > 0; off >>= 1){
    if (tid < off) red2[tid] = fminf(red2[tid], red2[tid+off]);
    __syncthreads();
  }
  if (tid == 0) atomicMin(&mmxa[0], fenc(red2[0]));
}

// ---------------- Ir/Vi maps (cat in O_IR, in-place) + folded activation outputs ----------------
// grid 4096, block 256. NT stores (write-once outputs).
__global__ void k_maps(const float* __restrict__ am,
                       const unsigned* __restrict__ mmxa, float* __restrict__ out){
  int bid = blockIdx.x;
  int tid = threadIdx.x;
  float mn = fdec(mmxa[0]);
  float inv = 1.0f / (fdec(mmxa[1]) - mn + 1e-10f);
  long e = ((long)bid*256 + tid) * 4;
  f4 c = *(const f4*)&out[O_IR + e];
  f4 a = *(const f4*)&am[(e >> 20)*16384 + (e & 16383)];
  f4 nam = (a - mn) * inv;
  f4 ir = nam * c;
  f4 vi = (1.0f - nam) * c;
  __builtin_nontemporal_store(ir, (f4*)&out[O_IR + e]);
  __builtin_nontemporal_store(vi, (f4*)&out[O_VI + e]);
  if (tid < 4){
    long e2 = ((long)bid*4 + tid) * 4;   // 16384 quads = 65536 floats
    f4 a2 = *(const f4*)&am[e2];
    f4 nam2 = (a2 - mn) * inv;
    f4 via = 1.0f - nam2;
    __builtin_nontemporal_store(nam2, (f4*)&out[O_IRA + e2]);
    __builtin_nontemporal_store(via,  (f4*)&out[O_VIA + e2]);
  }
}

// ---------------- fuse: stage E tile in LDS (f32, swizzled), MFMA fw, epilogue ----------------
// grid 4096 = 8t * 4b * 128 nt(128 n). block 256 = 4 waves; wave w -> 32 n.
// LDS tile [n 128][c 64] f32; element (c,n) at float-idx n*64 + (((c>>2)^(n&15))<<2) + (c&3).
// M/Mflat stores are NON-TEMPORAL: write-once, never re-read -> don't thrash L3 (keep E resident).
__global__ __launch_bounds__(256, 4) void k_fuse(EPtrs eps, const u16* __restrict__ Wb,
    const float* __restrict__ meanA, const float* __restrict__ mntA, const float* __restrict__ invA,
    float* __restrict__ out){
  int bid = blockIdx.x;
  int t = bid >> 9; int rem = bid & 511; int b = rem >> 7; int nt = rem & 127;
  const float* E = eps.p[t];
  const u16* Wp = Wb + (long)(t*4 + b)*4096;
  __shared__ float tileF[8192];       // 32 KB
  int tid = threadIdx.x; int lane = tid & 63; int w = tid >> 6;
  int jc = lane & 15, lq = lane >> 4;
  long n0 = (long)nt * 128;
  long eb = (long)(b*64) * NPIX;
  bf16x8 A[2][4];
  #pragma unroll
  for (int ks = 0; ks < 2; ++ks)
    #pragma unroll
    for (int mi = 0; mi < 4; ++mi)
      A[ks][mi] = *(const bf16x8*)&Wp[(mi*16 + jc)*64 + ks*32 + lq*8];
  #pragma unroll
  for (int it = 0; it < 8; ++it){
    int a = it*4 + w;                  // 0..31
    int c0 = (a >> 1) << 2;
    int n = (a & 1)*64 + lane;
    long src = eb + (long)c0*NPIX + n0 + n;
    float f0 = E[src];
    float f1 = E[src + NPIX];
    float f2 = E[src + 2*NPIX];
    float f3 = E[src + 3*NPIX];
    f32x4 v = {f0, f1, f2, f3};
    *(f32x4*)&tileF[n*64 + (((c0 >> 2) ^ (n & 15)) << 2)] = v;
  }
  __syncthreads();
  f32x4 acc[4][2];
  #pragma unroll
  for (int i=0;i<4;++i)
    #pragma unroll
    for (int j=0;j<2;++j) acc[i][j] = (f32x4){0.f,0.f,0.f,0.f};
  int nw = w*32;
  #pragma unroll
  for (int ks = 0; ks < 2; ++ks){
    #pragma unroll
    for (int j = 0; j < 2; ++j){
      int n_t = nw + j*16 + jc;        // n_t & 15 == jc
      int p = ks*8 + lq*2;
      const float* base = &tileF[n_t*64];
      f32x4 q0 = *(const f32x4*)&base[(p ^ jc) << 2];
      f32x4 q1 = *(const f32x4*)&base[((p+1) ^ jc) << 2];
      bf16x8 bv;
      bv[0]=(short)f2bf(q0[0]); bv[1]=(short)f2bf(q0[1]);
      bv[2]=(short)f2bf(q0[2]); bv[3]=(short)f2bf(q0[3]);
      bv[4]=(short)f2bf(q1[0]); bv[5]=(short)f2bf(q1[1]);
      bv[6]=(short)f2bf(q1[2]); bv[7]=(short)f2bf(q1[3]);
      #pragma unroll
      for (int mi = 0; mi < 4; ++mi)
        acc[mi][j] = __builtin_amdgcn_mfma_f32_16x16x32_bf16(A[ks][mi], bv, acc[mi][j], 0, 0, 0);
    }
  }
  float mean = meanA[t], mnt = mntA[t], inv = invA[t];
  long Mbase = (t & 1) ? O_M2 : O_M1;
  long gr = t >> 1;
  #pragma unroll
  for (int mi = 0; mi < 4; ++mi){
    #pragma unroll
    for (int j = 0; j < 2; ++j){
      int n_t = nw + j*16 + jc;
      f32x4 fv = *(const f32x4*)&tileF[n_t*64 + (((mi*4 + lq) ^ jc) << 2)];
      #pragma unroll
      for (int rr = 0; rr < 4; ++rr){
        int c = mi*16 + lq*4 + rr;
        float f = fv[rr];
        float tv = fmaxf(f - mean, 1e-10f);
        float val = (tv - mnt)*inv + acc[mi][j][rr] + f;
        long dst = Mbase + ((long)(b*256 + gr*64 + c))*NPIX + n0 + n_t;
        __builtin_nontemporal_store(val, &out[dst]);
        __builtin_nontemporal_store(val, &out[dst + FLATD]);
      }
    }
  }
}

extern "C" void kernel_launch(void* const* d_in, const int* in_sizes, int n_in,
                              void* d_out, int out_size, void* d_ws, size_t ws_size,
                              hipStream_t stream){
  (void)in_sizes; (void)n_in; (void)out_size; (void)ws_size;
  EPtrs ep;
  for (int i = 0; i < 8; ++i) ep.p[i] = (const float*)d_in[i];
  const float* fc = (const float*)d_in[8];
  const float* w1 = (const float*)d_in[9];
  const float* b1 = (const float*)d_in[10];
  const float* w2 = (const float*)d_in[11];
  const float* b2 = (const float*)d_in[12];
  float* out = (float*)d_out;
  char* ws = (char*)d_ws;
  float* sump   = (float*)(ws + WS_SUMP);
  unsigned* mmxe = (unsigned*)(ws + WS_MMXE);
  unsigned* mmxa = (unsigned*)(ws + WS_MMXA);
  float* meanA  = (float*)(ws + WS_MEAN);
  float* mntA   = (float*)(ws + WS_MNT);
  float* invA   = (float*)(ws + WS_INV);
  u16*   w1m    = (u16*)(ws + WS_W1M);
  float* am     = (float*)(ws + WS_AM);
  u16*   Wb     = (u16*)(ws + WS_WB);
  // d_out-aliased scratch:
  float* gram = out + O_M1F;            // written stats, read softmax, overwritten fuse
  float* cat  = out + O_IR;             // written conv1, read conv2 + maps(in-place)

  k_prep      <<<288, 256, 0, stream>>>(w1, w1m, mmxe, mmxa);
  k_conv1     <<<512, 512, 0, stream>>>(fc, w1m, b1, cat);
  k_conv2     <<<512, 256, 0, stream>>>(cat, w2, b2, am, mmxa);
  k_maps      <<<4096,256, 0, stream>>>(am, mmxa, out);
  k_stats_gram<<<1024,256, 0, stream>>>(ep, gram, sump, mmxe);
  k_softmax   <<<32, 1024, 0, stream>>>(gram, Wb, sump, mmxe, meanA, mntA, invA);
  k_fuse      <<<4096,256, 0, stream>>>(ep, Wb, meanA, mntA, invA, out);
}

// Round 9
// 201.108 us; speedup vs baseline: 1.3380x; 1.0238x over previous
//
#include <hip/hip_runtime.h>
#include <stdint.h>
#include <math.h>

typedef float f4 __attribute__((ext_vector_type(4)));
typedef float f32x4 __attribute__((ext_vector_type(4)));
typedef short bf16x8 __attribute__((ext_vector_type(8)));
typedef _Float16 f16x8 __attribute__((ext_vector_type(8)));
typedef unsigned short u16;
typedef unsigned short u16x4 __attribute__((ext_vector_type(4)));

#define NPIX 16384

// d_out offsets (floats). Return order: M1, M2, M1flat, M2flat, Ir_map, Vi_map, IrA, ViA
#define O_M1   0l
#define O_M2   16777216l
#define O_M1F  33554432l
#define O_M2F  50331648l
#define O_IR   67108864l
#define O_VI   71303168l
#define O_IRA  75497472l
#define O_VIA  75563008l
#define FLATD  33554432l   // offset from M to its flat duplicate (same for M1,M2)

// ws offsets (bytes)
#define WS_SUMP 0        // 1024 floats (8t * 4b * 32s)
#define WS_MMXE 4096     // 16 uints (per tensor min/max encoded)
#define WS_MMXA 4160     // 2 uints (activation map min/max)
#define WS_MEAN 4224     // 8 floats
#define WS_MNT  4256     // 8 floats
#define WS_INV  4288     // 8 floats
#define WS_W1M  8192     // 73728 u16, w1 as f16 relaid [icc][k9][oc][ic32]
#define WS_AM   262144   // 65536 floats (activation map, 256 KB)
#define WS_WB   524288   // 262144 u16 (softmax W bf16, 512 KB)

struct EPtrs { const float* p[8]; };

__device__ __forceinline__ u16 f2bf(float x){
  unsigned u = __float_as_uint(x);
  unsigned r = (u + 0x7fffu + ((u >> 16) & 1u)) >> 16;   // RNE
  return (u16)r;
}
__device__ __forceinline__ float bf2f(u16 v){
  return __uint_as_float(((unsigned)v) << 16);
}
__device__ __forceinline__ u16 f2h(float x){
  _Float16 h = (_Float16)x;
  u16 r; __builtin_memcpy(&r, &h, 2);
  return r;
}
// monotone float<->uint map for deterministic atomic min/max
__device__ __forceinline__ unsigned fenc(float x){
  unsigned u = __float_as_uint(x);
  return (u & 0x80000000u) ? ~u : (u | 0x80000000u);
}
__device__ __forceinline__ float fdec(unsigned u){
  unsigned v = (u & 0x80000000u) ? (u & 0x7fffffffu) : ~u;
  return __uint_as_float(v);
}

// ---------------- weight re-layout (+ atomic init in block 0) ----------------
__global__ void k_prep(const float* __restrict__ w1, u16* __restrict__ w1m,
                       unsigned* mmxe, unsigned* mmxa){
  if (blockIdx.x == 0 && threadIdx.x < 9){
    int t = threadIdx.x;
    if (t < 8){ mmxe[2*t] = 0xFFFFFFFFu; mmxe[2*t+1] = 0u; }
    else      { mmxa[0] = 0xFFFFFFFFu; mmxa[1] = 0u; }
  }
  int i = blockIdx.x*256 + threadIdx.x;
  if (i < 73728){
    int ic32 = i & 31;
    int oc   = (i >> 5) & 63;
    int k9   = (i >> 11) % 9;
    int icc  = i / 18432;
    float v = w1[(oc*128 + icc*32 + ic32)*9 + k9];
    w1m[i] = f2h(v);
  }
}

// ---------------- per-tensor stats + Gram partials (MFMA bf16) ----------------
// grid 1024 = 8 tensors * 4 batch * 32 slices(512 n each). block 256.
__global__ __launch_bounds__(256) void k_stats_gram(EPtrs eps,
    float* __restrict__ gram, float* __restrict__ sump, unsigned* __restrict__ mmxe){
  int bid = blockIdx.x;
  int t = bid >> 7; int rb = bid & 127; int b = rb >> 5; int s = rb & 31;
  const float* E = eps.p[t];
  __shared__ u16 lds[64*136];           // [c][n(128)+pad8] bf16
  __shared__ float red[768];
  int tid = threadIdx.x;
  int lane = tid & 63, wave = tid >> 6;
  f32x4 acc[4];
  #pragma unroll
  for (int i=0;i<4;++i) acc[i] = (f32x4){0.f,0.f,0.f,0.f};
  float vmin = 3.4e38f, vmax = -3.4e38f, vsum = 0.f;
  int rowS = tid >> 5;            // 0..7
  int colS = (tid & 31) * 4;      // 0..124
  int rA = wave*16 + (lane & 15);
  int kb = (lane >> 4) * 8;
  long nbase = (long)s * 512;
  for (int ch = 0; ch < 4; ++ch){
    long n0 = nbase + ch*128;
    __syncthreads();
    #pragma unroll
    for (int p = 0; p < 8; ++p){
      int row = p*8 + rowS;
      f4 v = *(const f4*)&E[(long)(b*64 + row)*NPIX + n0 + colS];
      vsum += v[0]+v[1]+v[2]+v[3];
      vmin = fminf(vmin, fminf(fminf(v[0],v[1]), fminf(v[2],v[3])));
      vmax = fmaxf(vmax, fmaxf(fmaxf(v[0],v[1]), fmaxf(v[2],v[3])));
      u16x4 w; w[0]=f2bf(v[0]); w[1]=f2bf(v[1]); w[2]=f2bf(v[2]); w[3]=f2bf(v[3]);
      *(u16x4*)&lds[row*136 + colS] = w;
    }
    __syncthreads();
    #pragma unroll
    for (int ks = 0; ks < 4; ++ks){
      bf16x8 a = *(bf16x8*)&lds[rA*136 + ks*32 + kb];
      #pragma unroll
      for (int cb = 0; cb < 4; ++cb){
        bf16x8 bb = *(bf16x8*)&lds[(cb*16 + (lane&15))*136 + ks*32 + kb];
        acc[cb] = __builtin_amdgcn_mfma_f32_16x16x32_bf16(a, bb, acc[cb], 0, 0, 0);
      }
    }
  }
  // gram partial write: S[c][d], c = 16*wave + 4*(lane>>4)+rr, d = 16*cb + (lane&15)
  long gbase = ((long)((t*4 + b)*32 + s)) * 4096;
  #pragma unroll
  for (int cb = 0; cb < 4; ++cb){
    int d = cb*16 + (lane & 15);
    #pragma unroll
    for (int rr = 0; rr < 4; ++rr){
      int c = 16*wave + 4*(lane>>4) + rr;
      gram[gbase + c*64 + d] = acc[cb][rr];
    }
  }
  // stats reduce
  red[tid] = vsum; red[256+tid] = vmin; red[512+tid] = vmax;
  __syncthreads();
  for (int off = 128; off > 0; off >>= 1){
    if (tid < off){
      red[tid] += red[tid+off];
      red[256+tid] = fminf(red[256+tid], red[256+tid+off]);
      red[512+tid] = fmaxf(red[512+tid], red[512+tid+off]);
    }
    __syncthreads();
  }
  if (tid == 0){
    sump[t*128 + b*32 + s] = red[0];
    atomicMin(&mmxe[2*t], fenc(red[256]));
    atomicMax(&mmxe[2*t+1], fenc(red[512]));
  }
}

// ---------------- gram 32-slice reduce + softmax over axis=1 + scalar finalize ----------------
// grid 32 = (t,b). block 1024. W[c][d] bf16 written to Wb (ws).
__global__ __launch_bounds__(1024) void k_softmax(const float* __restrict__ gram,
                          u16* __restrict__ Wb,
                          const float* __restrict__ sump, const unsigned* __restrict__ mmxe,
                          float* __restrict__ meanA, float* __restrict__ mntA, float* __restrict__ invA){
  int bid = blockIdx.x; int t = bid >> 2; int b = bid & 3;
  __shared__ float S[64*68];
  int tid = threadIdx.x;
  if (b == 0 && tid == 0){
    float s = 0.f;
    for (int j = 0; j < 128; ++j) s += sump[t*128 + j];
    float mean = s / 4194304.0f;
    float mn = fdec(mmxe[2*t]), mx = fdec(mmxe[2*t+1]);
    float mnt = fmaxf(mn - mean, 1e-10f);
    float mxt = fmaxf(mx - mean, 1e-10f);
    meanA[t] = mean; mntA[t] = mnt;
    invA[t] = 1.0f / (mxt - mnt + 1e-10f);
  }
  // reduce 32 partial grams (L2/L3-hot) -> S; same s-order as before (bit-identical)
  long gb = (long)(t*4 + b)*32*4096;
  {
    int i = tid;                        // 1024 threads * 4 elems = 4096
    f4 a = (f4){0.f,0.f,0.f,0.f};
    #pragma unroll
    for (int s = 0; s < 32; ++s) a += *(const f4*)&gram[gb + s*4096 + i*4];
    int c = i >> 4, d0 = (i & 15)*4;
    *(f4*)&S[c*68 + d0] = a;
  }
  __syncthreads();
  if (tid < 64){
    int d = tid;
    float mx = -3.4e38f;
    for (int c = 0; c < 64; ++c) mx = fmaxf(mx, S[c*68+d]);
    float sum = 0.f;
    for (int c = 0; c < 64; ++c){ float e = expf(S[c*68+d]-mx); S[c*68+d] = e; sum += e; }
    float inv = 1.0f/sum;
    long wb = (long)(t*4 + b)*4096;
    for (int c = 0; c < 64; ++c) Wb[wb + c*64 + d] = f2bf(S[c*68+d]*inv);
  }
}

// ---------------- conv1 3x3 implicit-GEMM MFMA f16 + bias + leaky ----------------
// grid 512 = (b,h) XCD-swizzled. block 512 = 8 waves: wave = (mg 2) x (ng 4).
__global__ __launch_bounds__(512) void k_conv1(const float* __restrict__ fc,
    const u16* __restrict__ w1m, const float* __restrict__ b1, float* __restrict__ cat){
  int bid = blockIdx.x;
  int vb = (bid & 7)*64 + (bid >> 3);      // XCD-chunked: contiguous h-bands per XCD
  int b = vb >> 7, h = vb & 127;
  __shared__ u16 xin[32*3*140];            // [ic32][r3][s140] f16 bits; s = w_in + 4
  int tid = threadIdx.x;
  int lane = tid & 63, wv = tid >> 6;
  int mg = wv >> 2, ng = wv & 3;
  int l15 = lane & 15, lq = lane >> 4;
  if (tid < 192){
    int ic = tid / 6, rem = tid % 6;
    int r = rem >> 1, sx = (rem & 1) ? 132 : 3;
    xin[(ic*3 + r)*140 + sx] = 0;
  }
  f32x4 acc[2][2];
  #pragma unroll
  for (int i=0;i<2;++i)
    #pragma unroll
    for (int j=0;j<2;++j) acc[i][j] = (f32x4){0.f,0.f,0.f,0.f};
  for (int icc = 0; icc < 4; ++icc){
    __syncthreads();
    #pragma unroll
    for (int it = 0; it < 6; ++it){
      int idx = tid + it*512;              // < 3072
      int ic = idx / 96, rem = idx % 96;
      int r = rem >> 5, q = rem & 31;
      int hr = h + r - 1;
      f4 v = (f4){0.f,0.f,0.f,0.f};
      if ((unsigned)hr < 128u)
        v = *(const f4*)&fc[(long)((b*128 + icc*32 + ic)*128 + hr)*128 + 4*q];
      u16x4 w; w[0]=f2h(v[0]); w[1]=f2h(v[1]); w[2]=f2h(v[2]); w[3]=f2h(v[3]);
      *(u16x4*)&xin[(ic*3 + r)*140 + 4 + 4*q] = w;
    }
    __syncthreads();
    #pragma unroll
    for (int kh = 0; kh < 3; ++kh){
      #pragma unroll
      for (int kw = 0; kw < 3; ++kw){
        int k9 = kh*3 + kw;
        f16x8 A[2];
        #pragma unroll
        for (int mi = 0; mi < 2; ++mi){
          int m = mg*2 + mi;
          A[mi] = *(const f16x8*)&w1m[(((icc*9 + k9)*64) + m*16 + l15)*32 + lq*8];
        }
        #pragma unroll
        for (int ji = 0; ji < 2; ++ji){
          int s = ng*32 + ji*16 + l15 + kw + 3;
          int kb = lq*8;
          f16x8 bv;
          #pragma unroll
          for (int e = 0; e < 8; ++e){
            u16 raw = xin[((kb + e)*3 + kh)*140 + s];
            _Float16 hh; __builtin_memcpy(&hh, &raw, 2);
            bv[e] = hh;
          }
          acc[0][ji] = __builtin_amdgcn_mfma_f32_16x16x32_f16(A[0], bv, acc[0][ji], 0, 0, 0);
          acc[1][ji] = __builtin_amdgcn_mfma_f32_16x16x32_f16(A[1], bv, acc[1][ji], 0, 0, 0);
        }
      }
    }
  }
  #pragma unroll
  for (int mi = 0; mi < 2; ++mi){
    #pragma unroll
    for (int rr = 0; rr < 4; ++rr){
      int oc = (mg*2 + mi)*16 + lq*4 + rr;
      float bb = b1[oc];
      #pragma unroll
      for (int ji = 0; ji < 2; ++ji){
        int w = ng*32 + ji*16 + l15;
        float v = acc[mi][ji][rr] + bb;
        v = v > 0.f ? v : 0.01f*v;
        cat[(long)((b*64 + oc)*128 + h)*128 + w] = v;
      }
    }
  }
}

// ---------------- conv2 3x3 (64ch -> 1) + bias, plus global min/max of result ----------------
// grid 512 = (b,h). block 256. am -> ws.
__global__ __launch_bounds__(256) void k_conv2(const float* __restrict__ cat,
    const float* __restrict__ w2, const float* __restrict__ b2p,
    float* __restrict__ am, unsigned* __restrict__ mmxa){
  int bid = blockIdx.x; int b = bid >> 7; int h = bid & 127;
  __shared__ u16 l2[64*3*136];
  __shared__ float w2l[576];
  __shared__ float red2[256];
  int tid = threadIdx.x;
  for (int i = tid; i < 576; i += 256) w2l[i] = w2[i];
  if (tid < 192){
    int ic = tid / 3, r = tid % 3;
    l2[ic*408 + r*136 + 3]   = 0;   // w_in = -1
    l2[ic*408 + r*136 + 132] = 0;   // w_in = 128
  }
  #pragma unroll
  for (int rep = 0; rep < 3; ++rep){
    int idx = rep*256 + tid;             // < 768 = 64ic * 3r * 4q
    int ic = idx / 12; int rem = idx - ic*12; int r = rem >> 2; int q = rem & 3;
    int hr = h + r - 1;
    #pragma unroll
    for (int k = 0; k < 8; ++k){
      int w = q*32 + 4*k;
      f4 v = (f4){0.f,0.f,0.f,0.f};
      if ((unsigned)hr < 128u)
        v = *(const f4*)&cat[(long)((b*64 + ic)*128 + hr)*128 + w];
      u16x4 u; u[0]=f2bf(v[0]); u[1]=f2bf(v[1]); u[2]=f2bf(v[2]); u[3]=f2bf(v[3]);
      *(u16x4*)&l2[ic*408 + r*136 + 4 + w] = u;
    }
  }
  __syncthreads();
  int w = tid & 127, icg = tid >> 7;
  float a = 0.f;
  for (int ic = icg*32; ic < icg*32+32; ++ic){
    #pragma unroll
    for (int r = 0; r < 3; ++r)
      #pragma unroll
      for (int kw = 0; kw < 3; ++kw)
        a = fmaf(bf2f(l2[ic*408 + r*136 + (w + kw + 3)]), w2l[ic*9 + r*3 + kw], a);
  }
  red2[tid] = a;
  __syncthreads();
  float av = 0.f;
  if (icg == 0){
    av = red2[w] + red2[128 + w] + b2p[0];
    am[(long)(b*128 + h)*128 + w] = av;
  }
  __syncthreads();
  red2[tid] = (icg == 0) ? av : -3.4e38f;
  __syncthreads();
  for (int off = 128; off > 0; off >>= 1){
    if (tid < off) red2[tid] = fmaxf(red2[tid], red2[tid+off]);
    __syncthreads();
  }
  if (tid == 0) atomicMax(&mmxa[1], fenc(red2[0]));
  __syncthreads();
  red2[tid] = (icg == 0) ? av : 3.4e38f;
  __syncthreads();
  for (int off = 128; off > 0; off >>= 1){
    if (tid < off) red2[tid] = fminf(red2[tid], red2[tid+off]);
    __syncthreads();
  }
  if (tid == 0) atomicMin(&mmxa[0], fenc(red2[0]));
}

// ---------------- Ir/Vi maps (cat in O_IR, in-place) + folded activation outputs ----------------
// grid 4096, block 256. NT stores (write-once outputs).
__global__ void k_maps(const float* __restrict__ am,
                       const unsigned* __restrict__ mmxa, float* __restrict__ out){
  int bid = blockIdx.x;
  int tid = threadIdx.x;
  float mn = fdec(mmxa[0]);
  float inv = 1.0f / (fdec(mmxa[1]) - mn + 1e-10f);
  long e = ((long)bid*256 + tid) * 4;
  f4 c = *(const f4*)&out[O_IR + e];
  f4 a = *(const f4*)&am[(e >> 20)*16384 + (e & 16383)];
  f4 nam = (a - mn) * inv;
  f4 ir = nam * c;
  f4 vi = (1.0f - nam) * c;
  __builtin_nontemporal_store(ir, (f4*)&out[O_IR + e]);
  __builtin_nontemporal_store(vi, (f4*)&out[O_VI + e]);
  if (tid < 4){
    long e2 = ((long)bid*4 + tid) * 4;   // 16384 quads = 65536 floats
    f4 a2 = *(const f4*)&am[e2];
    f4 nam2 = (a2 - mn) * inv;
    f4 via = 1.0f - nam2;
    __builtin_nontemporal_store(nam2, (f4*)&out[O_IRA + e2]);
    __builtin_nontemporal_store(via,  (f4*)&out[O_VIA + e2]);
  }
}

// ---------------- fuse: stage E tile in LDS (f32, swizzled), MFMA fw (D[n][c]), epilogue ----------------
// grid 4096 = 8t * 4b * 128 nt(128 n). block 256 = 4 waves; wave w -> 32 n.
// LDS tile [n 128][c 64] f32; element (c,n) at float-idx n*64 + (((c>>2)^(n&15))<<2) + (c&3).
// OPERAND-SWAPPED MFMA: A = fr-frag (rows n), B = W-frag (cols c) -> D[n][c];
// lane holds 4 consecutive n per acc -> ONE dwordx4 NT store per acc per dest (16 instead of 64).
// Same bf16 products / K-order as before -> bit-identical output.
__global__ __launch_bounds__(256, 4) void k_fuse(EPtrs eps, const u16* __restrict__ Wb,
    const float* __restrict__ meanA, const float* __restrict__ mntA, const float* __restrict__ invA,
    float* __restrict__ out){
  int bid = blockIdx.x;
  int t = bid >> 9; int rem = bid & 511; int b = rem >> 7; int nt = rem & 127;
  const float* E = eps.p[t];
  const u16* Wp = Wb + (long)(t*4 + b)*4096;
  __shared__ float tileF[8192];       // 32 KB
  int tid = threadIdx.x; int lane = tid & 63; int w = tid >> 6;
  int jc = lane & 15, lq = lane >> 4;
  long n0 = (long)nt * 128;
  long eb = (long)(b*64) * NPIX;
  // W fragments (now used as B operand; same loads as before): rows c = ci*16+jc, k = d
  bf16x8 Wf[2][4];
  #pragma unroll
  for (int ks = 0; ks < 2; ++ks)
    #pragma unroll
    for (int ci = 0; ci < 4; ++ci)
      Wf[ks][ci] = *(const bf16x8*)&Wp[(ci*16 + jc)*64 + ks*32 + lq*8];
  #pragma unroll
  for (int it = 0; it < 8; ++it){
    int a = it*4 + w;                  // 0..31
    int c0 = (a >> 1) << 2;
    int n = (a & 1)*64 + lane;
    long src = eb + (long)c0*NPIX + n0 + n;
    float f0 = E[src];
    float f1 = E[src + NPIX];
    float f2 = E[src + 2*NPIX];
    float f3 = E[src + 3*NPIX];
    f32x4 v = {f0, f1, f2, f3};
    *(f32x4*)&tileF[n*64 + (((c0 >> 2) ^ (n & 15)) << 2)] = v;
  }
  __syncthreads();
  f32x4 acc[2][4];                     // acc[j][ci]: D[n][c]
  #pragma unroll
  for (int i=0;i<2;++i)
    #pragma unroll
    for (int j=0;j<4;++j) acc[i][j] = (f32x4){0.f,0.f,0.f,0.f};
  int nw = w*32;
  #pragma unroll
  for (int ks = 0; ks < 2; ++ks){
    #pragma unroll
    for (int j = 0; j < 2; ++j){
      int n_t = nw + j*16 + jc;        // A-frag row n = jc; k = d
      int p = ks*8 + lq*2;
      const float* base = &tileF[n_t*64];
      f32x4 q0 = *(const f32x4*)&base[(p ^ jc) << 2];
      f32x4 q1 = *(const f32x4*)&base[((p+1) ^ jc) << 2];
      bf16x8 av;
      av[0]=(short)f2bf(q0[0]); av[1]=(short)f2bf(q0[1]);
      av[2]=(short)f2bf(q0[2]); av[3]=(short)f2bf(q0[3]);
      av[4]=(short)f2bf(q1[0]); av[5]=(short)f2bf(q1[1]);
      av[6]=(short)f2bf(q1[2]); av[7]=(short)f2bf(q1[3]);
      #pragma unroll
      for (int ci = 0; ci < 4; ++ci)
        acc[j][ci] = __builtin_amdgcn_mfma_f32_16x16x32_bf16(av, Wf[ks][ci], acc[j][ci], 0, 0, 0);
    }
  }
  float mean = meanA[t], mnt = mntA[t], inv = invA[t];
  long Mbase = (t & 1) ? O_M2 : O_M1;
  long gr = t >> 1;
  #pragma unroll
  for (int j = 0; j < 2; ++j){
    int nbase2 = nw + j*16 + lq*4;     // 4 consecutive n per lane
    #pragma unroll
    for (int ci = 0; ci < 4; ++ci){
      int c = ci*16 + jc;
      f4 vals;
      #pragma unroll
      for (int rr = 0; rr < 4; ++rr){
        int n_t = nbase2 + rr;
        float f = tileF[n_t*64 + ((((c >> 2) ^ (n_t & 15)) << 2) + (c & 3))];
        float tv = fmaxf(f - mean, 1e-10f);
        vals[rr] = (tv - mnt)*inv + acc[j][ci][rr] + f;
      }
      long dst = Mbase + ((long)(b*256 + gr*64 + c))*NPIX + n0 + nbase2;
      __builtin_nontemporal_store(vals, (f4*)&out[dst]);
      __builtin_nontemporal_store(vals, (f4*)&out[dst + FLATD]);
    }
  }
}

extern "C" void kernel_launch(void* const* d_in, const int* in_sizes, int n_in,
                              void* d_out, int out_size, void* d_ws, size_t ws_size,
                              hipStream_t stream){
  (void)in_sizes; (void)n_in; (void)out_size; (void)ws_size;
  EPtrs ep;
  for (int i = 0; i < 8; ++i) ep.p[i] = (const float*)d_in[i];
  const float* fc = (const float*)d_in[8];
  const float* w1 = (const float*)d_in[9];
  const float* b1 = (const float*)d_in[10];
  const float* w2 = (const float*)d_in[11];
  const float* b2 = (const float*)d_in[12];
  float* out = (float*)d_out;
  char* ws = (char*)d_ws;
  float* sump   = (float*)(ws + WS_SUMP);
  unsigned* mmxe = (unsigned*)(ws + WS_MMXE);
  unsigned* mmxa = (unsigned*)(ws + WS_MMXA);
  float* meanA  = (float*)(ws + WS_MEAN);
  float* mntA   = (float*)(ws + WS_MNT);
  float* invA   = (float*)(ws + WS_INV);
  u16*   w1m    = (u16*)(ws + WS_W1M);
  float* am     = (float*)(ws + WS_AM);
  u16*   Wb     = (u16*)(ws + WS_WB);
  // d_out-aliased scratch:
  float* gram = out + O_M1F;            // written stats, read softmax, overwritten fuse
  float* cat  = out + O_IR;             // written conv1, read conv2 + maps(in-place)

  k_prep      <<<288, 256, 0, stream>>>(w1, w1m, mmxe, mmxa);
  k_conv1     <<<512, 512, 0, stream>>>(fc, w1m, b1, cat);
  k_conv2     <<<512, 256, 0, stream>>>(cat, w2, b2, am, mmxa);
  k_maps      <<<4096,256, 0, stream>>>(am, mmxa, out);
  k_stats_gram<<<1024,256, 0, stream>>>(ep, gram, sump, mmxe);
  k_softmax   <<<32, 1024, 0, stream>>>(gram, Wb, sump, mmxe, meanA, mntA, invA);
  k_fuse      <<<4096,256, 0, stream>>>(ep, Wb, meanA, mntA, invA, out);
}

// Round 10
// 197.811 us; speedup vs baseline: 1.3603x; 1.0167x over previous
//
#include <hip/hip_runtime.h>
#include <stdint.h>
#include <math.h>

typedef float f4 __attribute__((ext_vector_type(4)));
typedef float f32x4 __attribute__((ext_vector_type(4)));
typedef short bf16x8 __attribute__((ext_vector_type(8)));
typedef _Float16 f16x8 __attribute__((ext_vector_type(8)));
typedef unsigned short u16;
typedef unsigned short u16x4 __attribute__((ext_vector_type(4)));

#define NPIX 16384

// d_out offsets (floats). Return order: M1, M2, M1flat, M2flat, Ir_map, Vi_map, IrA, ViA
#define O_M1   0l
#define O_M2   16777216l
#define O_M1F  33554432l
#define O_M2F  50331648l
#define O_IR   67108864l
#define O_VI   71303168l
#define O_IRA  75497472l
#define O_VIA  75563008l
#define FLATD  33554432l   // offset from M to its flat duplicate (same for M1,M2)

// ws offsets (bytes)
#define WS_SUMP 0        // 1024 floats (8t * 4b * 32s)
#define WS_MMXE 4096     // 16 uints (per tensor min/max encoded)
#define WS_MMXA 4160     // 2 uints (activation map min/max)
#define WS_MEAN 4224     // 8 floats
#define WS_MNT  4256     // 8 floats
#define WS_INV  4288     // 8 floats
#define WS_W1M  8192     // 73728 u16, w1 as f16 relaid [icc][k9][oc][ic32]
#define WS_AM   262144   // 65536 floats (activation map, 256 KB)
#define WS_WB   524288   // 262144 u16 (softmax W bf16, 512 KB)

struct EPtrs { const float* p[8]; };

__device__ __forceinline__ u16 f2bf(float x){
  unsigned u = __float_as_uint(x);
  unsigned r = (u + 0x7fffu + ((u >> 16) & 1u)) >> 16;   // RNE
  return (u16)r;
}
__device__ __forceinline__ float bf2f(u16 v){
  return __uint_as_float(((unsigned)v) << 16);
}
__device__ __forceinline__ u16 f2h(float x){
  _Float16 h = (_Float16)x;
  u16 r; __builtin_memcpy(&r, &h, 2);
  return r;
}
// monotone float<->uint map for deterministic atomic min/max
__device__ __forceinline__ unsigned fenc(float x){
  unsigned u = __float_as_uint(x);
  return (u & 0x80000000u) ? ~u : (u | 0x80000000u);
}
__device__ __forceinline__ float fdec(unsigned u){
  unsigned v = (u & 0x80000000u) ? (u & 0x7fffffffu) : ~u;
  return __uint_as_float(v);
}

// ---------------- weight re-layout (+ atomic init in block 0) ----------------
__global__ void k_prep(const float* __restrict__ w1, u16* __restrict__ w1m,
                       unsigned* mmxe, unsigned* mmxa){
  if (blockIdx.x == 0 && threadIdx.x < 9){
    int t = threadIdx.x;
    if (t < 8){ mmxe[2*t] = 0xFFFFFFFFu; mmxe[2*t+1] = 0u; }
    else      { mmxa[0] = 0xFFFFFFFFu; mmxa[1] = 0u; }
  }
  int i = blockIdx.x*256 + threadIdx.x;
  if (i < 73728){
    int ic32 = i & 31;
    int oc   = (i >> 5) & 63;
    int k9   = (i >> 11) % 9;
    int icc  = i / 18432;
    float v = w1[(oc*128 + icc*32 + ic32)*9 + k9];
    w1m[i] = f2h(v);
  }
}

// ================= k_A: stats_gram (bid<1024) || conv1 (bid>=1024), block 256 =================
// Block-range split keeps each sub-grid's XCD (mod 8) mapping (split at 1024 = 8-aligned).
struct SGsh { u16 lds[64*136]; float red[768]; };
struct C1sh { u16 xin[32*3*140]; };
union  KAsh { SGsh sg; C1sh c1; };

__global__ __launch_bounds__(256) void k_A(EPtrs eps,
    const float* __restrict__ fc, const u16* __restrict__ w1m, const float* __restrict__ b1,
    float* __restrict__ gram, float* __restrict__ sump, unsigned* __restrict__ mmxe,
    float* __restrict__ cat){
  __shared__ KAsh sh;
  int bid = blockIdx.x;
  int tid = threadIdx.x;
  int lane = tid & 63, wave = tid >> 6;
  if (bid < 1024){
    // ---- stats + gram partials (identical math to R9 k_stats_gram) ----
    int t = bid >> 7; int rb = bid & 127; int b = rb >> 5; int s = rb & 31;
    const float* E = eps.p[t];
    f32x4 acc[4];
    #pragma unroll
    for (int i=0;i<4;++i) acc[i] = (f32x4){0.f,0.f,0.f,0.f};
    float vmin = 3.4e38f, vmax = -3.4e38f, vsum = 0.f;
    int rowS = tid >> 5;
    int colS = (tid & 31) * 4;
    int rA = wave*16 + (lane & 15);
    int kb = (lane >> 4) * 8;
    long nbase = (long)s * 512;
    for (int ch = 0; ch < 4; ++ch){
      long n0 = nbase + ch*128;
      __syncthreads();
      #pragma unroll
      for (int p = 0; p < 8; ++p){
        int row = p*8 + rowS;
        f4 v = *(const f4*)&E[(long)(b*64 + row)*NPIX + n0 + colS];
        vsum += v[0]+v[1]+v[2]+v[3];
        vmin = fminf(vmin, fminf(fminf(v[0],v[1]), fminf(v[2],v[3])));
        vmax = fmaxf(vmax, fmaxf(fmaxf(v[0],v[1]), fmaxf(v[2],v[3])));
        u16x4 w; w[0]=f2bf(v[0]); w[1]=f2bf(v[1]); w[2]=f2bf(v[2]); w[3]=f2bf(v[3]);
        *(u16x4*)&sh.sg.lds[row*136 + colS] = w;
      }
      __syncthreads();
      #pragma unroll
      for (int ks = 0; ks < 4; ++ks){
        bf16x8 a = *(bf16x8*)&sh.sg.lds[rA*136 + ks*32 + kb];
        #pragma unroll
        for (int cb = 0; cb < 4; ++cb){
          bf16x8 bb = *(bf16x8*)&sh.sg.lds[(cb*16 + (lane&15))*136 + ks*32 + kb];
          acc[cb] = __builtin_amdgcn_mfma_f32_16x16x32_bf16(a, bb, acc[cb], 0, 0, 0);
        }
      }
    }
    long gbase = ((long)((t*4 + b)*32 + s)) * 4096;
    #pragma unroll
    for (int cb = 0; cb < 4; ++cb){
      int d = cb*16 + (lane & 15);
      #pragma unroll
      for (int rr = 0; rr < 4; ++rr){
        int c = 16*wave + 4*(lane>>4) + rr;
        gram[gbase + c*64 + d] = acc[cb][rr];
      }
    }
    sh.sg.red[tid] = vsum; sh.sg.red[256+tid] = vmin; sh.sg.red[512+tid] = vmax;
    __syncthreads();
    for (int off = 128; off > 0; off >>= 1){
      if (tid < off){
        sh.sg.red[tid] += sh.sg.red[tid+off];
        sh.sg.red[256+tid] = fminf(sh.sg.red[256+tid], sh.sg.red[256+tid+off]);
        sh.sg.red[512+tid] = fmaxf(sh.sg.red[512+tid], sh.sg.red[512+tid+off]);
      }
      __syncthreads();
    }
    if (tid == 0){
      sump[t*128 + b*32 + s] = sh.sg.red[0];
      atomicMin(&mmxe[2*t], fenc(sh.sg.red[256]));
      atomicMax(&mmxe[2*t+1], fenc(sh.sg.red[512]));
    }
  } else {
    // ---- conv1 implicit-GEMM MFMA f16 (same LDS layout/math as R9, 4-wave mapping) ----
    int cb = bid - 1024;
    int vb = (cb & 7)*64 + (cb >> 3);      // XCD-chunked h-bands (preserved)
    int b = vb >> 7, h = vb & 127;
    int mg = wave >> 1, ng = wave & 1;
    int l15 = lane & 15, lq = lane >> 4;
    if (tid < 192){
      int ic = tid / 6, rem = tid % 6;
      int r = rem >> 1, sx = (rem & 1) ? 132 : 3;
      sh.c1.xin[(ic*3 + r)*140 + sx] = 0;
    }
    f32x4 acc[2][4];
    #pragma unroll
    for (int i=0;i<2;++i)
      #pragma unroll
      for (int j=0;j<4;++j) acc[i][j] = (f32x4){0.f,0.f,0.f,0.f};
    for (int icc = 0; icc < 4; ++icc){
      __syncthreads();
      #pragma unroll
      for (int it = 0; it < 12; ++it){
        int idx = it*256 + tid;              // < 3072
        int ic = idx / 96, rem = idx % 96;
        int r = rem >> 5, q = rem & 31;
        int hr = h + r - 1;
        f4 v = (f4){0.f,0.f,0.f,0.f};
        if ((unsigned)hr < 128u)
          v = *(const f4*)&fc[(long)((b*128 + icc*32 + ic)*128 + hr)*128 + 4*q];
        u16x4 w; w[0]=f2h(v[0]); w[1]=f2h(v[1]); w[2]=f2h(v[2]); w[3]=f2h(v[3]);
        *(u16x4*)&sh.c1.xin[(ic*3 + r)*140 + 4 + 4*q] = w;
      }
      __syncthreads();
      #pragma unroll
      for (int kh = 0; kh < 3; ++kh){
        #pragma unroll
        for (int kw = 0; kw < 3; ++kw){
          int k9 = kh*3 + kw;
          f16x8 A[2];
          #pragma unroll
          for (int mi = 0; mi < 2; ++mi){
            int m = mg*2 + mi;
            A[mi] = *(const f16x8*)&w1m[(((icc*9 + k9)*64) + m*16 + l15)*32 + lq*8];
          }
          #pragma unroll
          for (int ji = 0; ji < 4; ++ji){
            int s = ng*64 + ji*16 + l15 + kw + 3;
            int kb = lq*8;
            f16x8 bv;
            #pragma unroll
            for (int e = 0; e < 8; ++e){
              u16 raw = sh.c1.xin[((kb + e)*3 + kh)*140 + s];
              _Float16 hh; __builtin_memcpy(&hh, &raw, 2);
              bv[e] = hh;
            }
            acc[0][ji] = __builtin_amdgcn_mfma_f32_16x16x32_f16(A[0], bv, acc[0][ji], 0, 0, 0);
            acc[1][ji] = __builtin_amdgcn_mfma_f32_16x16x32_f16(A[1], bv, acc[1][ji], 0, 0, 0);
          }
        }
      }
    }
    #pragma unroll
    for (int mi = 0; mi < 2; ++mi){
      #pragma unroll
      for (int rr = 0; rr < 4; ++rr){
        int oc = (mg*2 + mi)*16 + lq*4 + rr;
        float bb = b1[oc];
        #pragma unroll
        for (int ji = 0; ji < 4; ++ji){
          int w = ng*64 + ji*16 + l15;
          float v = acc[mi][ji][rr] + bb;
          v = v > 0.f ? v : 0.01f*v;
          cat[(long)((b*64 + oc)*128 + h)*128 + w] = v;
        }
      }
    }
  }
}

// ================= k_B: conv2 (bid<512) || gramred+softmax (bid>=512), block 256 =================
struct C2sh { u16 l2[64*3*136]; float w2l[576]; float red2[256]; };
struct SMsh { float S[64*68]; };
union  KBsh { C2sh c2; SMsh sm; };

__global__ __launch_bounds__(256) void k_B(const float* __restrict__ gram,
    u16* __restrict__ Wb, const float* __restrict__ sump, const unsigned* __restrict__ mmxe,
    float* __restrict__ meanA, float* __restrict__ mntA, float* __restrict__ invA,
    const float* __restrict__ cat, const float* __restrict__ w2, const float* __restrict__ b2p,
    float* __restrict__ am, unsigned* __restrict__ mmxa){
  __shared__ KBsh sh;
  int bid = blockIdx.x;
  int tid = threadIdx.x;
  if (bid < 512){
    // ---- conv2 3x3 (64ch->1) + bias + global min/max (identical to R9) ----
    int b = bid >> 7; int h = bid & 127;
    for (int i = tid; i < 576; i += 256) sh.c2.w2l[i] = w2[i];
    if (tid < 192){
      int ic = tid / 3, r = tid % 3;
      sh.c2.l2[ic*408 + r*136 + 3]   = 0;
      sh.c2.l2[ic*408 + r*136 + 132] = 0;
    }
    #pragma unroll
    for (int rep = 0; rep < 3; ++rep){
      int idx = rep*256 + tid;
      int ic = idx / 12; int rem = idx - ic*12; int r = rem >> 2; int q = rem & 3;
      int hr = h + r - 1;
      #pragma unroll
      for (int k = 0; k < 8; ++k){
        int w = q*32 + 4*k;
        f4 v = (f4){0.f,0.f,0.f,0.f};
        if ((unsigned)hr < 128u)
          v = *(const f4*)&cat[(long)((b*64 + ic)*128 + hr)*128 + w];
        u16x4 u; u[0]=f2bf(v[0]); u[1]=f2bf(v[1]); u[2]=f2bf(v[2]); u[3]=f2bf(v[3]);
        *(u16x4*)&sh.c2.l2[ic*408 + r*136 + 4 + w] = u;
      }
    }
    __syncthreads();
    int w = tid & 127, icg = tid >> 7;
    float a = 0.f;
    for (int ic = icg*32; ic < icg*32+32; ++ic){
      #pragma unroll
      for (int r = 0; r < 3; ++r)
        #pragma unroll
        for (int kw = 0; kw < 3; ++kw)
          a = fmaf(bf2f(sh.c2.l2[ic*408 + r*136 + (w + kw + 3)]), sh.c2.w2l[ic*9 + r*3 + kw], a);
    }
    sh.c2.red2[tid] = a;
    __syncthreads();
    float av = 0.f;
    if (icg == 0){
      av = sh.c2.red2[w] + sh.c2.red2[128 + w] + b2p[0];
      am[(long)(b*128 + h)*128 + w] = av;
    }
    __syncthreads();
    sh.c2.red2[tid] = (icg == 0) ? av : -3.4e38f;
    __syncthreads();
    for (int off = 128; off > 0; off >>= 1){
      if (tid < off) sh.c2.red2[tid] = fmaxf(sh.c2.red2[tid], sh.c2.red2[tid+off]);
      __syncthreads();
    }
    if (tid == 0) atomicMax(&mmxa[1], fenc(sh.c2.red2[0]));
    __syncthreads();
    sh.c2.red2[tid] = (icg == 0) ? av : 3.4e38f;
    __syncthreads();
    for (int off = 128; off > 0; off >>= 1){
      if (tid < off) sh.c2.red2[tid] = fminf(sh.c2.red2[tid], sh.c2.red2[tid+off]);
      __syncthreads();
    }
    if (tid == 0) atomicMin(&mmxa[0], fenc(sh.c2.red2[0]));
  } else {
    // ---- gram 32-slice reduce + softmax + scalar finalize (same math, 256-thread strided) ----
    int sb = bid - 512;
    int t = sb >> 2; int b = sb & 3;
    if (b == 0 && tid == 0){
      float s = 0.f;
      for (int j = 0; j < 128; ++j) s += sump[t*128 + j];
      float mean = s / 4194304.0f;
      float mn = fdec(mmxe[2*t]), mx = fdec(mmxe[2*t+1]);
      float mnt = fmaxf(mn - mean, 1e-10f);
      float mxt = fmaxf(mx - mean, 1e-10f);
      meanA[t] = mean; mntA[t] = mnt;
      invA[t] = 1.0f / (mxt - mnt + 1e-10f);
    }
    long gb = (long)(t*4 + b)*32*4096;
    for (int i = tid; i < 1024; i += 256){
      f4 a = (f4){0.f,0.f,0.f,0.f};
      #pragma unroll
      for (int s = 0; s < 32; ++s) a += *(const f4*)&gram[gb + s*4096 + i*4];
      int c = i >> 4, d0 = (i & 15)*4;
      *(f4*)&sh.sm.S[c*68 + d0] = a;
    }
    __syncthreads();
    if (tid < 64){
      int d = tid;
      float mx = -3.4e38f;
      for (int c = 0; c < 64; ++c) mx = fmaxf(mx, sh.sm.S[c*68+d]);
      float sum = 0.f;
      for (int c = 0; c < 64; ++c){ float e = expf(sh.sm.S[c*68+d]-mx); sh.sm.S[c*68+d] = e; sum += e; }
      float inv = 1.0f/sum;
      long wb = (long)(t*4 + b)*4096;
      for (int c = 0; c < 64; ++c) Wb[wb + c*64 + d] = f2bf(sh.sm.S[c*68+d]*inv);
    }
  }
}

// ---------------- Ir/Vi maps (cat in O_IR, in-place) + folded activation outputs ----------------
// grid 4096, block 256. NT stores (write-once outputs).
__global__ void k_maps(const float* __restrict__ am,
                       const unsigned* __restrict__ mmxa, float* __restrict__ out){
  int bid = blockIdx.x;
  int tid = threadIdx.x;
  float mn = fdec(mmxa[0]);
  float inv = 1.0f / (fdec(mmxa[1]) - mn + 1e-10f);
  long e = ((long)bid*256 + tid) * 4;
  f4 c = *(const f4*)&out[O_IR + e];
  f4 a = *(const f4*)&am[(e >> 20)*16384 + (e & 16383)];
  f4 nam = (a - mn) * inv;
  f4 ir = nam * c;
  f4 vi = (1.0f - nam) * c;
  __builtin_nontemporal_store(ir, (f4*)&out[O_IR + e]);
  __builtin_nontemporal_store(vi, (f4*)&out[O_VI + e]);
  if (tid < 4){
    long e2 = ((long)bid*4 + tid) * 4;   // 16384 quads = 65536 floats
    f4 a2 = *(const f4*)&am[e2];
    f4 nam2 = (a2 - mn) * inv;
    f4 via = 1.0f - nam2;
    __builtin_nontemporal_store(nam2, (f4*)&out[O_IRA + e2]);
    __builtin_nontemporal_store(via,  (f4*)&out[O_VIA + e2]);
  }
}

// ---------------- fuse: stage E tile in LDS (f32, swizzled), MFMA fw (D[n][c]), NT epilogue ----------------
// grid 4096 = 8t * 4b * 128 nt(128 n). block 256 = 4 waves; wave w -> 32 n.
// LDS tile [n 128][c 64] f32; element (c,n) at float-idx n*64 + (((c>>2)^(n&15))<<2) + (c&3).
// OPERAND-SWAPPED MFMA -> D[n][c]; one dwordx4 NT store per acc per dest.
__global__ __launch_bounds__(256, 4) void k_fuse(EPtrs eps, const u16* __restrict__ Wb,
    const float* __restrict__ meanA, const float* __restrict__ mntA, const float* __restrict__ invA,
    float* __restrict__ out){
  int bid = blockIdx.x;
  int t = bid >> 9; int rem = bid & 511; int b = rem >> 7; int nt = rem & 127;
  const float* E = eps.p[t];
  const u16* Wp = Wb + (long)(t*4 + b)*4096;
  __shared__ float tileF[8192];       // 32 KB
  int tid = threadIdx.x; int lane = tid & 63; int w = tid >> 6;
  int jc = lane & 15, lq = lane >> 4;
  long n0 = (long)nt * 128;
  long eb = (long)(b*64) * NPIX;
  bf16x8 Wf[2][4];
  #pragma unroll
  for (int ks = 0; ks < 2; ++ks)
    #pragma unroll
    for (int ci = 0; ci < 4; ++ci)
      Wf[ks][ci] = *(const bf16x8*)&Wp[(ci*16 + jc)*64 + ks*32 + lq*8];
  #pragma unroll
  for (int it = 0; it < 8; ++it){
    int a = it*4 + w;                  // 0..31
    int c0 = (a >> 1) << 2;
    int n = (a & 1)*64 + lane;
    long src = eb + (long)c0*NPIX + n0 + n;
    float f0 = E[src];
    float f1 = E[src + NPIX];
    float f2 = E[src + 2*NPIX];
    float f3 = E[src + 3*NPIX];
    f32x4 v = {f0, f1, f2, f3};
    *(f32x4*)&tileF[n*64 + (((c0 >> 2) ^ (n & 15)) << 2)] = v;
  }
  __syncthreads();
  f32x4 acc[2][4];                     // acc[j][ci]: D[n][c]
  #pragma unroll
  for (int i=0;i<2;++i)
    #pragma unroll
    for (int j=0;j<4;++j) acc[i][j] = (f32x4){0.f,0.f,0.f,0.f};
  int nw = w*32;
  #pragma unroll
  for (int ks = 0; ks < 2; ++ks){
    #pragma unroll
    for (int j = 0; j < 2; ++j){
      int n_t = nw + j*16 + jc;        // A-frag row n = jc; k = d
      int p = ks*8 + lq*2;
      const float* base = &tileF[n_t*64];
      f32x4 q0 = *(const f32x4*)&base[(p ^ jc) << 2];
      f32x4 q1 = *(const f32x4*)&base[((p+1) ^ jc) << 2];
      bf16x8 av;
      av[0]=(short)f2bf(q0[0]); av[1]=(short)f2bf(q0[1]);
      av[2]=(short)f2bf(q0[2]); av[3]=(short)f2bf(q0[3]);
      av[4]=(short)f2bf(q1[0]); av[5]=(short)f2bf(q1[1]);
      av[6]=(short)f2bf(q1[2]); av[7]=(short)f2bf(q1[3]);
      #pragma unroll
      for (int ci = 0; ci < 4; ++ci)
        acc[j][ci] = __builtin_amdgcn_mfma_f32_16x16x32_bf16(av, Wf[ks][ci], acc[j][ci], 0, 0, 0);
    }
  }
  float mean = meanA[t], mnt = mntA[t], inv = invA[t];
  long Mbase = (t & 1) ? O_M2 : O_M1;
  long gr = t >> 1;
  #pragma unroll
  for (int j = 0; j < 2; ++j){
    int nbase2 = nw + j*16 + lq*4;     // 4 consecutive n per lane
    #pragma unroll
    for (int ci = 0; ci < 4; ++ci){
      int c = ci*16 + jc;
      f4 vals;
      #pragma unroll
      for (int rr = 0; rr < 4; ++rr){
        int n_t = nbase2 + rr;
        float f = tileF[n_t*64 + ((((c >> 2) ^ (n_t & 15)) << 2) + (c & 3))];
        float tv = fmaxf(f - mean, 1e-10f);
        vals[rr] = (tv - mnt)*inv + acc[j][ci][rr] + f;
      }
      long dst = Mbase + ((long)(b*256 + gr*64 + c))*NPIX + n0 + nbase2;
      __builtin_nontemporal_store(vals, (f4*)&out[dst]);
      __builtin_nontemporal_store(vals, (f4*)&out[dst + FLATD]);
    }
  }
}

extern "C" void kernel_launch(void* const* d_in, const int* in_sizes, int n_in,
                              void* d_out, int out_size, void* d_ws, size_t ws_size,
                              hipStream_t stream){
  (void)in_sizes; (void)n_in; (void)out_size; (void)ws_size;
  EPtrs ep;
  for (int i = 0; i < 8; ++i) ep.p[i] = (const float*)d_in[i];
  const float* fc = (const float*)d_in[8];
  const float* w1 = (const float*)d_in[9];
  const float* b1 = (const float*)d_in[10];
  const float* w2 = (const float*)d_in[11];
  const float* b2 = (const float*)d_in[12];
  float* out = (float*)d_out;
  char* ws = (char*)d_ws;
  float* sump   = (float*)(ws + WS_SUMP);
  unsigned* mmxe = (unsigned*)(ws + WS_MMXE);
  unsigned* mmxa = (unsigned*)(ws + WS_MMXA);
  float* meanA  = (float*)(ws + WS_MEAN);
  float* mntA   = (float*)(ws + WS_MNT);
  float* invA   = (float*)(ws + WS_INV);
  u16*   w1m    = (u16*)(ws + WS_W1M);
  float* am     = (float*)(ws + WS_AM);
  u16*   Wb     = (u16*)(ws + WS_WB);
  // d_out-aliased scratch:
  float* gram = out + O_M1F;            // written k_A(stats), read k_B(softmax), overwritten k_fuse
  float* cat  = out + O_IR;             // written k_A(conv1), read k_B(conv2) + k_maps(in-place)

  k_prep <<<288,  256, 0, stream>>>(w1, w1m, mmxe, mmxa);
  k_A    <<<1536, 256, 0, stream>>>(ep, fc, w1m, b1, gram, sump, mmxe, cat);
  k_B    <<<544,  256, 0, stream>>>(gram, Wb, sump, mmxe, meanA, mntA, invA,
                                    cat, w2, b2, am, mmxa);
  k_maps <<<4096, 256, 0, stream>>>(am, mmxa, out);
  k_fuse <<<4096, 256, 0, stream>>>(ep, Wb, meanA, mntA, invA, out);
}

// Round 11
// 193.927 us; speedup vs baseline: 1.3876x; 1.0200x over previous
//
#include <hip/hip_runtime.h>
#include <stdint.h>
#include <math.h>

typedef float f4 __attribute__((ext_vector_type(4)));
typedef float f32x4 __attribute__((ext_vector_type(4)));
typedef short bf16x8 __attribute__((ext_vector_type(8)));
typedef _Float16 f16x8 __attribute__((ext_vector_type(8)));
typedef unsigned short u16;
typedef unsigned short u16x4 __attribute__((ext_vector_type(4)));

#define NPIX 16384

// d_out offsets (floats). Return order: M1, M2, M1flat, M2flat, Ir_map, Vi_map, IrA, ViA
#define O_M1   0l
#define O_M2   16777216l
#define O_M1F  33554432l
#define O_M2F  50331648l
#define O_IR   67108864l
#define O_VI   71303168l
#define O_IRA  75497472l
#define O_VIA  75563008l
#define FLATD  33554432l   // offset from M to its flat duplicate (same for M1,M2)

// ws offsets (bytes)
#define WS_SUMP 0        // 1024 floats (8t * 4b * 32s)
#define WS_MMXE 4096     // 16 uints (per tensor min/max encoded)
#define WS_MMXA 4160     // 2 uints (activation map min/max)
#define WS_MEAN 4224     // 8 floats
#define WS_MNT  4256     // 8 floats
#define WS_INV  4288     // 8 floats
#define WS_W1M  8192     // 73728 u16, w1 as f16 relaid [icc][k9][oc][ic32]
#define WS_AM   262144   // 65536 floats (activation map, 256 KB)
#define WS_WB   524288   // 262144 u16 (softmax W bf16, 512 KB)

struct EPtrs { const float* p[8]; };

__device__ __forceinline__ u16 f2bf(float x){
  unsigned u = __float_as_uint(x);
  unsigned r = (u + 0x7fffu + ((u >> 16) & 1u)) >> 16;   // RNE
  return (u16)r;
}
__device__ __forceinline__ float bf2f(u16 v){
  return __uint_as_float(((unsigned)v) << 16);
}
__device__ __forceinline__ u16 f2h(float x){
  _Float16 h = (_Float16)x;
  u16 r; __builtin_memcpy(&r, &h, 2);
  return r;
}
// monotone float<->uint map for deterministic atomic min/max
__device__ __forceinline__ unsigned fenc(float x){
  unsigned u = __float_as_uint(x);
  return (u & 0x80000000u) ? ~u : (u | 0x80000000u);
}
__device__ __forceinline__ float fdec(unsigned u){
  unsigned v = (u & 0x80000000u) ? (u & 0x7fffffffu) : ~u;
  return __uint_as_float(v);
}

// ---------------- weight re-layout (+ atomic init in block 0) ----------------
__global__ void k_prep(const float* __restrict__ w1, u16* __restrict__ w1m,
                       unsigned* mmxe, unsigned* mmxa){
  if (blockIdx.x == 0 && threadIdx.x < 9){
    int t = threadIdx.x;
    if (t < 8){ mmxe[2*t] = 0xFFFFFFFFu; mmxe[2*t+1] = 0u; }
    else      { mmxa[0] = 0xFFFFFFFFu; mmxa[1] = 0u; }
  }
  int i = blockIdx.x*256 + threadIdx.x;
  if (i < 73728){
    int ic32 = i & 31;
    int oc   = (i >> 5) & 63;
    int k9   = (i >> 11) % 9;
    int icc  = i / 18432;
    float v = w1[(oc*128 + icc*32 + ic32)*9 + k9];
    w1m[i] = f2h(v);
  }
}

// ================= k_A: stats_gram (bid<1024) || conv1 (bid>=1024), block 256 =================
// Block-range split keeps each sub-grid's XCD (mod 8) mapping (split at 1024 = 8-aligned).
struct SGsh { u16 lds[64*136]; float red[768]; };
struct C1sh { u16 xin[32*3*140]; };
union  KAsh { SGsh sg; C1sh c1; };

__global__ __launch_bounds__(256) void k_A(EPtrs eps,
    const float* __restrict__ fc, const u16* __restrict__ w1m, const float* __restrict__ b1,
    float* __restrict__ gram, float* __restrict__ sump, unsigned* __restrict__ mmxe,
    float* __restrict__ cat){
  __shared__ KAsh sh;
  int bid = blockIdx.x;
  int tid = threadIdx.x;
  int lane = tid & 63, wave = tid >> 6;
  if (bid < 1024){
    // ---- stats + gram partials ----
    int t = bid >> 7; int rb = bid & 127; int b = rb >> 5; int s = rb & 31;
    const float* E = eps.p[t];
    f32x4 acc[4];
    #pragma unroll
    for (int i=0;i<4;++i) acc[i] = (f32x4){0.f,0.f,0.f,0.f};
    float vmin = 3.4e38f, vmax = -3.4e38f, vsum = 0.f;
    int rowS = tid >> 5;
    int colS = (tid & 31) * 4;
    int rA = wave*16 + (lane & 15);
    int kb = (lane >> 4) * 8;
    long nbase = (long)s * 512;
    for (int ch = 0; ch < 4; ++ch){
      long n0 = nbase + ch*128;
      __syncthreads();
      #pragma unroll
      for (int p = 0; p < 8; ++p){
        int row = p*8 + rowS;
        f4 v = *(const f4*)&E[(long)(b*64 + row)*NPIX + n0 + colS];
        vsum += v[0]+v[1]+v[2]+v[3];
        vmin = fminf(vmin, fminf(fminf(v[0],v[1]), fminf(v[2],v[3])));
        vmax = fmaxf(vmax, fmaxf(fmaxf(v[0],v[1]), fmaxf(v[2],v[3])));
        u16x4 w; w[0]=f2bf(v[0]); w[1]=f2bf(v[1]); w[2]=f2bf(v[2]); w[3]=f2bf(v[3]);
        *(u16x4*)&sh.sg.lds[row*136 + colS] = w;
      }
      __syncthreads();
      #pragma unroll
      for (int ks = 0; ks < 4; ++ks){
        bf16x8 a = *(bf16x8*)&sh.sg.lds[rA*136 + ks*32 + kb];
        #pragma unroll
        for (int cb = 0; cb < 4; ++cb){
          bf16x8 bb = *(bf16x8*)&sh.sg.lds[(cb*16 + (lane&15))*136 + ks*32 + kb];
          acc[cb] = __builtin_amdgcn_mfma_f32_16x16x32_bf16(a, bb, acc[cb], 0, 0, 0);
        }
      }
    }
    long gbase = ((long)((t*4 + b)*32 + s)) * 4096;
    #pragma unroll
    for (int cb = 0; cb < 4; ++cb){
      int d = cb*16 + (lane & 15);
      #pragma unroll
      for (int rr = 0; rr < 4; ++rr){
        int c = 16*wave + 4*(lane>>4) + rr;
        gram[gbase + c*64 + d] = acc[cb][rr];
      }
    }
    sh.sg.red[tid] = vsum; sh.sg.red[256+tid] = vmin; sh.sg.red[512+tid] = vmax;
    __syncthreads();
    for (int off = 128; off > 0; off >>= 1){
      if (tid < off){
        sh.sg.red[tid] += sh.sg.red[tid+off];
        sh.sg.red[256+tid] = fminf(sh.sg.red[256+tid], sh.sg.red[256+tid+off]);
        sh.sg.red[512+tid] = fmaxf(sh.sg.red[512+tid], sh.sg.red[512+tid+off]);
      }
      __syncthreads();
    }
    if (tid == 0){
      sump[t*128 + b*32 + s] = sh.sg.red[0];
      atomicMin(&mmxe[2*t], fenc(sh.sg.red[256]));
      atomicMax(&mmxe[2*t+1], fenc(sh.sg.red[512]));
    }
  } else {
    // ---- conv1 implicit-GEMM MFMA f16 ----
    int cb = bid - 1024;
    int vb = (cb & 7)*64 + (cb >> 3);      // XCD-chunked h-bands (preserved)
    int b = vb >> 7, h = vb & 127;
    int mg = wave >> 1, ng = wave & 1;
    int l15 = lane & 15, lq = lane >> 4;
    if (tid < 192){
      int ic = tid / 6, rem = tid % 6;
      int r = rem >> 1, sx = (rem & 1) ? 132 : 3;
      sh.c1.xin[(ic*3 + r)*140 + sx] = 0;
    }
    f32x4 acc[2][4];
    #pragma unroll
    for (int i=0;i<2;++i)
      #pragma unroll
      for (int j=0;j<4;++j) acc[i][j] = (f32x4){0.f,0.f,0.f,0.f};
    for (int icc = 0; icc < 4; ++icc){
      __syncthreads();
      #pragma unroll
      for (int it = 0; it < 12; ++it){
        int idx = it*256 + tid;              // < 3072
        int ic = idx / 96, rem = idx % 96;
        int r = rem >> 5, q = rem & 31;
        int hr = h + r - 1;
        f4 v = (f4){0.f,0.f,0.f,0.f};
        if ((unsigned)hr < 128u)
          v = *(const f4*)&fc[(long)((b*128 + icc*32 + ic)*128 + hr)*128 + 4*q];
        u16x4 w; w[0]=f2h(v[0]); w[1]=f2h(v[1]); w[2]=f2h(v[2]); w[3]=f2h(v[3]);
        *(u16x4*)&sh.c1.xin[(ic*3 + r)*140 + 4 + 4*q] = w;
      }
      __syncthreads();
      #pragma unroll
      for (int kh = 0; kh < 3; ++kh){
        #pragma unroll
        for (int kw = 0; kw < 3; ++kw){
          int k9 = kh*3 + kw;
          f16x8 A[2];
          #pragma unroll
          for (int mi = 0; mi < 2; ++mi){
            int m = mg*2 + mi;
            A[mi] = *(const f16x8*)&w1m[(((icc*9 + k9)*64) + m*16 + l15)*32 + lq*8];
          }
          #pragma unroll
          for (int ji = 0; ji < 4; ++ji){
            int s = ng*64 + ji*16 + l15 + kw + 3;
            int kb = lq*8;
            f16x8 bv;
            #pragma unroll
            for (int e = 0; e < 8; ++e){
              u16 raw = sh.c1.xin[((kb + e)*3 + kh)*140 + s];
              _Float16 hh; __builtin_memcpy(&hh, &raw, 2);
              bv[e] = hh;
            }
            acc[0][ji] = __builtin_amdgcn_mfma_f32_16x16x32_f16(A[0], bv, acc[0][ji], 0, 0, 0);
            acc[1][ji] = __builtin_amdgcn_mfma_f32_16x16x32_f16(A[1], bv, acc[1][ji], 0, 0, 0);
          }
        }
      }
    }
    #pragma unroll
    for (int mi = 0; mi < 2; ++mi){
      #pragma unroll
      for (int rr = 0; rr < 4; ++rr){
        int oc = (mg*2 + mi)*16 + lq*4 + rr;
        float bb = b1[oc];
        #pragma unroll
        for (int ji = 0; ji < 4; ++ji){
          int w = ng*64 + ji*16 + l15;
          float v = acc[mi][ji][rr] + bb;
          v = v > 0.f ? v : 0.01f*v;
          cat[(long)((b*64 + oc)*128 + h)*128 + w] = v;
        }
      }
    }
  }
}

// ================= k_B: conv2 (bid<512) || gramred+softmax (bid>=512), block 256 =================
struct C2sh { u16 l2[64*3*136]; float w2l[576]; float red2[256]; };
struct SMsh { float S[64*68]; };
union  KBsh { C2sh c2; SMsh sm; };

__global__ __launch_bounds__(256) void k_B(const float* __restrict__ gram,
    u16* __restrict__ Wb, const float* __restrict__ sump, const unsigned* __restrict__ mmxe,
    float* __restrict__ meanA, float* __restrict__ mntA, float* __restrict__ invA,
    const float* __restrict__ cat, const float* __restrict__ w2, const float* __restrict__ b2p,
    float* __restrict__ am, unsigned* __restrict__ mmxa){
  __shared__ KBsh sh;
  int bid = blockIdx.x;
  int tid = threadIdx.x;
  if (bid < 512){
    // ---- conv2 3x3 (64ch->1) + bias + global min/max ----
    int b = bid >> 7; int h = bid & 127;
    for (int i = tid; i < 576; i += 256) sh.c2.w2l[i] = w2[i];
    if (tid < 192){
      int ic = tid / 3, r = tid % 3;
      sh.c2.l2[ic*408 + r*136 + 3]   = 0;
      sh.c2.l2[ic*408 + r*136 + 132] = 0;
    }
    #pragma unroll
    for (int rep = 0; rep < 3; ++rep){
      int idx = rep*256 + tid;
      int ic = idx / 12; int rem = idx - ic*12; int r = rem >> 2; int q = rem & 3;
      int hr = h + r - 1;
      #pragma unroll
      for (int k = 0; k < 8; ++k){
        int w = q*32 + 4*k;
        f4 v = (f4){0.f,0.f,0.f,0.f};
        if ((unsigned)hr < 128u)
          v = *(const f4*)&cat[(long)((b*64 + ic)*128 + hr)*128 + w];
        u16x4 u; u[0]=f2bf(v[0]); u[1]=f2bf(v[1]); u[2]=f2bf(v[2]); u[3]=f2bf(v[3]);
        *(u16x4*)&sh.c2.l2[ic*408 + r*136 + 4 + w] = u;
      }
    }
    __syncthreads();
    int w = tid & 127, icg = tid >> 7;
    float a = 0.f;
    for (int ic = icg*32; ic < icg*32+32; ++ic){
      #pragma unroll
      for (int r = 0; r < 3; ++r)
        #pragma unroll
        for (int kw = 0; kw < 3; ++kw)
          a = fmaf(bf2f(sh.c2.l2[ic*408 + r*136 + (w + kw + 3)]), sh.c2.w2l[ic*9 + r*3 + kw], a);
    }
    sh.c2.red2[tid] = a;
    __syncthreads();
    float av = 0.f;
    if (icg == 0){
      av = sh.c2.red2[w] + sh.c2.red2[128 + w] + b2p[0];
      am[(long)(b*128 + h)*128 + w] = av;
    }
    __syncthreads();
    sh.c2.red2[tid] = (icg == 0) ? av : -3.4e38f;
    __syncthreads();
    for (int off = 128; off > 0; off >>= 1){
      if (tid < off) sh.c2.red2[tid] = fmaxf(sh.c2.red2[tid], sh.c2.red2[tid+off]);
      __syncthreads();
    }
    if (tid == 0) atomicMax(&mmxa[1], fenc(sh.c2.red2[0]));
    __syncthreads();
    sh.c2.red2[tid] = (icg == 0) ? av : 3.4e38f;
    __syncthreads();
    for (int off = 128; off > 0; off >>= 1){
      if (tid < off) sh.c2.red2[tid] = fminf(sh.c2.red2[tid], sh.c2.red2[tid+off]);
      __syncthreads();
    }
    if (tid == 0) atomicMin(&mmxa[0], fenc(sh.c2.red2[0]));
  } else {
    // ---- gram 32-slice reduce + softmax + scalar finalize ----
    int sb = bid - 512;
    int t = sb >> 2; int b = sb & 3;
    if (b == 0 && tid == 0){
      float s = 0.f;
      for (int j = 0; j < 128; ++j) s += sump[t*128 + j];
      float mean = s / 4194304.0f;
      float mn = fdec(mmxe[2*t]), mx = fdec(mmxe[2*t+1]);
      float mnt = fmaxf(mn - mean, 1e-10f);
      float mxt = fmaxf(mx - mean, 1e-10f);
      meanA[t] = mean; mntA[t] = mnt;
      invA[t] = 1.0f / (mxt - mnt + 1e-10f);
    }
    long gb = (long)(t*4 + b)*32*4096;
    for (int i = tid; i < 1024; i += 256){
      f4 a = (f4){0.f,0.f,0.f,0.f};
      #pragma unroll
      for (int s = 0; s < 32; ++s) a += *(const f4*)&gram[gb + s*4096 + i*4];
      int c = i >> 4, d0 = (i & 15)*4;
      *(f4*)&sh.sm.S[c*68 + d0] = a;
    }
    __syncthreads();
    if (tid < 64){
      int d = tid;
      float mx = -3.4e38f;
      for (int c = 0; c < 64; ++c) mx = fmaxf(mx, sh.sm.S[c*68+d]);
      float sum = 0.f;
      for (int c = 0; c < 64; ++c){ float e = expf(sh.sm.S[c*68+d]-mx); sh.sm.S[c*68+d] = e; sum += e; }
      float inv = 1.0f/sum;
      long wb = (long)(t*4 + b)*4096;
      for (int c = 0; c < 64; ++c) Wb[wb + c*64 + d] = f2bf(sh.sm.S[c*68+d]*inv);
    }
  }
}

// ================= k_C: fuse (bid<4096) || maps (bid>=4096), block 256 =================
// Split at 4096 (8-aligned): both sub-grids keep their XCD (mod 8) mapping.
// fuse: stage E tile in LDS (f32, swizzled), operand-swapped MFMA -> D[n][c], NT dwordx4 epilogue.
// maps: Ir/Vi from cat (in O_IR, in-place) + folded IrA/ViA outputs, all NT.
__global__ __launch_bounds__(256, 4) void k_C(EPtrs eps, const u16* __restrict__ Wb,
    const float* __restrict__ meanA, const float* __restrict__ mntA, const float* __restrict__ invA,
    const float* __restrict__ am, const unsigned* __restrict__ mmxa, float* __restrict__ out){
  __shared__ float tileF[8192];       // 32 KB (fuse role only)
  int bid = blockIdx.x;
  int tid = threadIdx.x;
  if (bid >= 4096){
    // ---- maps role ----
    int mb = bid - 4096;
    float mn = fdec(mmxa[0]);
    float inv = 1.0f / (fdec(mmxa[1]) - mn + 1e-10f);
    long e = ((long)mb*256 + tid) * 4;
    f4 c = *(const f4*)&out[O_IR + e];
    f4 a = *(const f4*)&am[(e >> 20)*16384 + (e & 16383)];
    f4 nam = (a - mn) * inv;
    f4 ir = nam * c;
    f4 vi = (1.0f - nam) * c;
    __builtin_nontemporal_store(ir, (f4*)&out[O_IR + e]);
    __builtin_nontemporal_store(vi, (f4*)&out[O_VI + e]);
    if (tid < 4){
      long e2 = ((long)mb*4 + tid) * 4;   // 16384 quads = 65536 floats
      f4 a2 = *(const f4*)&am[e2];
      f4 nam2 = (a2 - mn) * inv;
      f4 via = 1.0f - nam2;
      __builtin_nontemporal_store(nam2, (f4*)&out[O_IRA + e2]);
      __builtin_nontemporal_store(via,  (f4*)&out[O_VIA + e2]);
    }
    return;
  }
  // ---- fuse role ----
  int t = bid >> 9; int rem = bid & 511; int b = rem >> 7; int nt = rem & 127;
  const float* E = eps.p[t];
  const u16* Wp = Wb + (long)(t*4 + b)*4096;
  int lane = tid & 63; int w = tid >> 6;
  int jc = lane & 15, lq = lane >> 4;
  long n0 = (long)nt * 128;
  long eb = (long)(b*64) * NPIX;
  bf16x8 Wf[2][4];
  #pragma unroll
  for (int ks = 0; ks < 2; ++ks)
    #pragma unroll
    for (int ci = 0; ci < 4; ++ci)
      Wf[ks][ci] = *(const bf16x8*)&Wp[(ci*16 + jc)*64 + ks*32 + lq*8];
  #pragma unroll
  for (int it = 0; it < 8; ++it){
    int a = it*4 + w;                  // 0..31
    int c0 = (a >> 1) << 2;
    int n = (a & 1)*64 + lane;
    long src = eb + (long)c0*NPIX + n0 + n;
    float f0 = E[src];
    float f1 = E[src + NPIX];
    float f2 = E[src + 2*NPIX];
    float f3 = E[src + 3*NPIX];
    f32x4 v = {f0, f1, f2, f3};
    *(f32x4*)&tileF[n*64 + (((c0 >> 2) ^ (n & 15)) << 2)] = v;
  }
  __syncthreads();
  f32x4 acc[2][4];                     // acc[j][ci]: D[n][c]
  #pragma unroll
  for (int i=0;i<2;++i)
    #pragma unroll
    for (int j=0;j<4;++j) acc[i][j] = (f32x4){0.f,0.f,0.f,0.f};
  int nw = w*32;
  #pragma unroll
  for (int ks = 0; ks < 2; ++ks){
    #pragma unroll
    for (int j = 0; j < 2; ++j){
      int n_t = nw + j*16 + jc;        // A-frag row n = jc; k = d
      int p = ks*8 + lq*2;
      const float* base = &tileF[n_t*64];
      f32x4 q0 = *(const f32x4*)&base[(p ^ jc) << 2];
      f32x4 q1 = *(const f32x4*)&base[((p+1) ^ jc) << 2];
      bf16x8 av;
      av[0]=(short)f2bf(q0[0]); av[1]=(short)f2bf(q0[1]);
      av[2]=(short)f2bf(q0[2]); av[3]=(short)f2bf(q0[3]);
      av[4]=(short)f2bf(q1[0]); av[5]=(short)f2bf(q1[1]);
      av[6]=(short)f2bf(q1[2]); av[7]=(short)f2bf(q1[3]);
      #pragma unroll
      for (int ci = 0; ci < 4; ++ci)
        acc[j][ci] = __builtin_amdgcn_mfma_f32_16x16x32_bf16(av, Wf[ks][ci], acc[j][ci], 0, 0, 0);
    }
  }
  float mean = meanA[t], mnt = mntA[t], inv = invA[t];
  long Mbase = (t & 1) ? O_M2 : O_M1;
  long gr = t >> 1;
  #pragma unroll
  for (int j = 0; j < 2; ++j){
    int nbase2 = nw + j*16 + lq*4;     // 4 consecutive n per lane
    #pragma unroll
    for (int ci = 0; ci < 4; ++ci){
      int c = ci*16 + jc;
      f4 vals;
      #pragma unroll
      for (int rr = 0; rr < 4; ++rr){
        int n_t = nbase2 + rr;
        float f = tileF[n_t*64 + ((((c >> 2) ^ (n_t & 15)) << 2) + (c & 3))];
        float tv = fmaxf(f - mean, 1e-10f);
        vals[rr] = (tv - mnt)*inv + acc[j][ci][rr] + f;
      }
      long dst = Mbase + ((long)(b*256 + gr*64 + c))*NPIX + n0 + nbase2;
      __builtin_nontemporal_store(vals, (f4*)&out[dst]);
      __builtin_nontemporal_store(vals, (f4*)&out[dst + FLATD]);
    }
  }
}

extern "C" void kernel_launch(void* const* d_in, const int* in_sizes, int n_in,
                              void* d_out, int out_size, void* d_ws, size_t ws_size,
                              hipStream_t stream){
  (void)in_sizes; (void)n_in; (void)out_size; (void)ws_size;
  EPtrs ep;
  for (int i = 0; i < 8; ++i) ep.p[i] = (const float*)d_in[i];
  const float* fc = (const float*)d_in[8];
  const float* w1 = (const float*)d_in[9];
  const float* b1 = (const float*)d_in[10];
  const float* w2 = (const float*)d_in[11];
  const float* b2 = (const float*)d_in[12];
  float* out = (float*)d_out;
  char* ws = (char*)d_ws;
  float* sump   = (float*)(ws + WS_SUMP);
  unsigned* mmxe = (unsigned*)(ws + WS_MMXE);
  unsigned* mmxa = (unsigned*)(ws + WS_MMXA);
  float* meanA  = (float*)(ws + WS_MEAN);
  float* mntA   = (float*)(ws + WS_MNT);
  float* invA   = (float*)(ws + WS_INV);
  u16*   w1m    = (u16*)(ws + WS_W1M);
  float* am     = (float*)(ws + WS_AM);
  u16*   Wb     = (u16*)(ws + WS_WB);
  // d_out-aliased scratch:
  float* gram = out + O_M1F;            // written k_A(stats), read k_B(softmax), overwritten k_C(fuse)
  float* cat  = out + O_IR;             // written k_A(conv1), read k_B(conv2) + k_C(maps in-place)

  k_prep <<<288,  256, 0, stream>>>(w1, w1m, mmxe, mmxa);
  k_A    <<<1536, 256, 0, stream>>>(ep, fc, w1m, b1, gram, sump, mmxe, cat);
  k_B    <<<544,  256, 0, stream>>>(gram, Wb, sump, mmxe, meanA, mntA, invA,
                                    cat, w2, b2, am, mmxa);
  k_C    <<<8192, 256, 0, stream>>>(ep, Wb, meanA, mntA, invA, am, mmxa, out);
}